// Round 17
// baseline (808.690 us; speedup 1.0000x reference)
//
#include <hip/hip_runtime.h>

#define NN 20000
#define NE 160000
#define HD 128
#define SA 136   // LDS A-tile row stride (bf16 elems); 272B rows, 16B-aligned

typedef __attribute__((ext_vector_type(8))) short  bfrag;   // 8 bf16 = one MFMA A/B frag
typedef __attribute__((ext_vector_type(4))) short  s4v;     // half-frag (8B)
typedef __attribute__((ext_vector_type(4))) float  facc;    // MFMA C/D frag
typedef __attribute__((ext_vector_type(4))) float  f4v;

__device__ __forceinline__ float bf2f(unsigned short u){
  union { unsigned int i; float f; } v; v.i = ((unsigned int)u) << 16; return v.f;
}
__device__ __forceinline__ unsigned short f2bf(float f){
  union { float f; unsigned int i; } v; v.f = f;
  unsigned int r = v.i + 0x7fffu + ((v.i >> 16) & 1u);
  return (unsigned short)(r >> 16);
}

__global__ void sentinel_kernel(float* out, float code){
  if (threadIdx.x < 32) out[threadIdx.x] = code;
}

// A (LDS, [64][SA] bf16) @ B (global, fragment-packed 128x128 bf16) += acc[8]
// packed[((kt*8+nt)*64+lane)*8+j] = W[kt*32+(lane>>4)*8+j][nt*16+(lane&15)]
__device__ __forceinline__ void gemm_tile(const short* Ab,
                                          const unsigned short* pk,
                                          int m0, int lane, facc acc[8]){
  const int q = lane >> 4, c = lane & 15;
  #pragma unroll
  for (int kt = 0; kt < 4; ++kt){
    bfrag a = *(const bfrag*)(Ab + (m0 + c) * SA + kt * 32 + q * 8);
    const bfrag* bp = (const bfrag*)pk + kt * 512 + lane;
    #pragma unroll
    for (int nt = 0; nt < 8; ++nt){
      acc[nt] = __builtin_amdgcn_mfma_f32_16x16x32_bf16(a, bp[nt * 64], acc[nt], 0, 0, 0);
    }
  }
}

// nt-split half-tile: wave computes rows m0..m0+15 x cols [ntb*16, ntb*16+64).
// Per-acc accumulation order (kt outer, nt inner) identical to gemm_tile -> bitwise same.
__device__ __forceinline__ void gemm_tile_h(const short* Ab,
                                            const unsigned short* pk,
                                            int m0, int ntb, int lane, facc acc[4]){
  const int q = lane >> 4, c = lane & 15;
  #pragma unroll
  for (int kt = 0; kt < 4; ++kt){
    bfrag a = *(const bfrag*)(Ab + (m0 + c) * SA + kt * 32 + q * 8);
    const bfrag* bp = (const bfrag*)pk + kt * 512 + ntb * 64 + lane;
    #pragma unroll
    for (int nt = 0; nt < 4; ++nt){
      acc[nt] = __builtin_amdgcn_mfma_f32_16x16x32_bf16(a, bp[nt * 64], acc[nt], 0, 0, 0);
    }
  }
}

// 2-row-set variant: wave computes rows m0..m0+31 x cols [ntb*16, ntb*16+64).
// Each B fragment loaded ONCE feeds 2 MFMAs (row sets m0, m0+16) -> B L2-traffic halved.
// Per-acc order: acc0/acc1 each get one MFMA per kt in kt order -> bitwise identical
// to gemm_tile_h(m0) / gemm_tile_h(m0+16).
__device__ __forceinline__ void gemm_tile_h2(const short* Ab,
                                             const unsigned short* pk,
                                             int m0, int ntb, int lane,
                                             facc acc0[4], facc acc1[4]){
  const int q = lane >> 4, c = lane & 15;
  #pragma unroll
  for (int kt = 0; kt < 4; ++kt){
    bfrag a0 = *(const bfrag*)(Ab + (m0 +      c) * SA + kt * 32 + q * 8);
    bfrag a1 = *(const bfrag*)(Ab + (m0 + 16 + c) * SA + kt * 32 + q * 8);
    const bfrag* bp = (const bfrag*)pk + kt * 512 + ntb * 64 + lane;
    #pragma unroll
    for (int nt = 0; nt < 4; ++nt){
      bfrag b = bp[nt * 64];
      acc0[nt] = __builtin_amdgcn_mfma_f32_16x16x32_bf16(a0, b, acc0[nt], 0, 0, 0);
      acc1[nt] = __builtin_amdgcn_mfma_f32_16x16x32_bf16(a1, b, acc1[nt], 0, 0, 0);
    }
  }
}

// -------- pack 30 fp32 128x128 matrices -> hi/lo bf16 fragment planes (60 planes) --------
__global__ __launch_bounds__(256) void pack_all(
    const float* Wn2, const float* We2,
    const float* lEW1, const float* lEW2,
    const float* lVW1, const float* lVW2,
    unsigned short* packed)
{
  int job = blockIdx.x * 256 + threadIdx.x;   // 30 mats * 4096 (2 planes * 2048)
  int mat = job >> 12, r12 = job & 4095;
  int plane = r12 >> 11, r = r12 & 2047;
  int kt = r >> 9, nt = (r >> 6) & 7, lane = r & 63;
  const float* src;
  if (mat == 0) src = Wn2;
  else if (mat == 1) src = We2;
  else {
    int m2 = mat - 2, l = m2 / 7, t = m2 % 7;
    switch (t){
      case 0: src = lEW1 + ((size_t)l*512 +   0)*HD; break;   // P weights
      case 1: src = lEW1 + ((size_t)l*512 + 128)*HD; break;   // Q weights
      case 2: src = lEW1 + ((size_t)l*512 + 256)*HD; break;   // xe weights
      case 3: src = lEW2 + (size_t)l*HD*HD;          break;
      case 4: src = lVW1 + ((size_t)l*384 +   0)*HD; break;   // x_v weights
      case 5: src = lVW1 + ((size_t)l*384 + 128)*HD; break;   // aggr weights
      default: src = lVW2 + (size_t)l*HD*HD;         break;
    }
  }
  int krow = kt*32 + (lane>>4)*8, col = nt*16 + (lane&15);
  unsigned short v[8];
  #pragma unroll
  for (int j = 0; j < 8; ++j){
    float w = src[(size_t)(krow + j)*HD + col];
    unsigned short h = f2bf(w);
    v[j] = plane ? f2bf(w - bf2f(h)) : h;
  }
  unsigned short* dst = packed + ((size_t)mat*2 + plane)*16384
                               + ((size_t)(kt*8+nt)*64 + lane)*8;
  #pragma unroll
  for (int j = 0; j < 8; ++j) dst[j] = v[j];
}

// ---------------- init ----------------
__global__ __launch_bounds__(128) void init_small(
    float* g, float* cbe, float* cbv, float* xvs, float* xes,
    const float* Eb1_0, const float* Vb1_0)
{
  int t = threadIdx.x;
  g[t] = 0.f; xvs[t] = 0.f; xes[t] = 0.f;
  cbe[t] = Eb1_0[t]; cbv[t] = Vb1_0[t];
}

// ---------------- preprocessing: counting sort of edges by receiver ----------------
__global__ __launch_bounds__(256) void zero_cnt(int* cnt){
  int i = blockIdx.x * 256 + threadIdx.x;
  if (i < NN) cnt[i] = 0;
}
__global__ __launch_bounds__(256) void hist_kernel(const int* eidx, int* cnt){
  int e = blockIdx.x * 256 + threadIdx.x;
  atomicAdd(&cnt[eidx[NE + e]], 1);
}
// exclusive prefix sum over NN counts -> base[0..NN], plus mutable copy ofs
__global__ __launch_bounds__(1024) void scan_kernel(const int* cnt, int* base, int* ofs){
  __shared__ int wsum[16];
  int t = threadIdx.x, lane = t & 63;
  int vals[20]; int loc = 0;
  if (t < 1000){
    #pragma unroll
    for (int k = 0; k < 20; ++k){ vals[k] = cnt[t*20 + k]; loc += vals[k]; }
  }
  int inc = loc;
  #pragma unroll
  for (int d = 1; d < 64; d <<= 1){ int o = __shfl_up(inc, d); if (lane >= d) inc += o; }
  if (lane == 63) wsum[t >> 6] = inc;
  __syncthreads();
  if (t < 16){
    int v = wsum[t];
    #pragma unroll
    for (int d = 1; d < 16; d <<= 1){ int o = __shfl_up(v, d); if (t >= d) v += o; }
    wsum[t] = v;
  }
  __syncthreads();
  int woff = (t >= 64) ? wsum[(t >> 6) - 1] : 0;
  int run = woff + inc - loc;   // exclusive prefix for this thread's chunk
  if (t < 1000){
    #pragma unroll
    for (int k = 0; k < 20; ++k){ base[t*20 + k] = run; ofs[t*20 + k] = run; run += vals[k]; }
  }
  if (t == 0) base[NN] = NE;
}
__global__ __launch_bounds__(256) void scatter_kernel(const int* eidx, int* ofs,
                                                      int* perm, int* ssid, int* srid){
  int e = blockIdx.x * 256 + threadIdx.x;
  int s = eidx[e], r = eidx[NE + e];
  int pos = atomicAdd(&ofs[r], 1);
  perm[pos] = e; ssid[pos] = s; srid[pos] = r;
}

// ---------------- node encoder v2: 512 threads, 8 waves nt-split, LN half-exchange ------
__global__ __launch_bounds__(512, 4) void enc_node(
    const float* x, const float* W1, const float* b1,
    const unsigned short* pkW2, const float* b2,
    const float* gl, const float* bl, float* xvf, int nrows)
{
  __shared__ float inb[64*12];
  __shared__ __align__(16) short Hh[64*SA];
  __shared__ __align__(16) short Hl[64*SA];
  __shared__ float lnS[128], lnSS[128];        // [row*2 + half]
  int tid = threadIdx.x, r0 = blockIdx.x * 64;
  for (int j = tid; j < 64*12; j += 512){
    int rr = j / 12, k = j % 12, rg = r0 + rr;
    inb[j] = (rg < nrows) ? x[(size_t)rg*12 + k] : 0.f;
  }
  __syncthreads();
  {
    int cc = tid & 127;
    float w1c[12];
    #pragma unroll
    for (int k = 0; k < 12; ++k) w1c[k] = W1[k*HD + cc];
    float bb = b1[cc];
    for (int it = 0; it < 16; ++it){
      int rr = it*4 + (tid >> 7);
      float a = bb;
      #pragma unroll
      for (int k = 0; k < 12; ++k) a += inb[rr*12 + k] * w1c[k];
      float h = fmaxf(a, 0.f);
      unsigned short hh = f2bf(h);
      Hh[rr*SA + cc] = (short)hh;
      Hl[rr*SA + cc] = (short)f2bf(h - bf2f(hh));
    }
  }
  __syncthreads();
  int lane = tid & 63, wq = tid >> 6, q = lane >> 4, c = lane & 15;
  int m0 = (wq & 3) * 16, ntb = (wq >> 2) * 4, half = wq >> 2;
  facc a2[4];
  #pragma unroll
  for (int nt = 0; nt < 4; ++nt) a2[nt] = (facc){0.f,0.f,0.f,0.f};
  gemm_tile_h(Hh, pkW2,         m0, ntb, lane, a2);
  gemm_tile_h(Hl, pkW2,         m0, ntb, lane, a2);
  gemm_tile_h(Hh, pkW2 + 16384, m0, ntb, lane, a2);
  float vals[4][4], myS[4], mySS[4];
  #pragma unroll
  for (int i = 0; i < 4; ++i){
    int rl = m0 + q*4 + i;
    float s = 0.f, ss = 0.f;
    #pragma unroll
    for (int nt = 0; nt < 4; ++nt){
      float v = a2[nt][i] + b2[(ntb + nt)*16 + c];
      vals[i][nt] = v; s += v; ss += v*v;
    }
    s += __shfl_xor(s,1); ss += __shfl_xor(ss,1);
    s += __shfl_xor(s,2); ss += __shfl_xor(ss,2);
    s += __shfl_xor(s,4); ss += __shfl_xor(ss,4);
    s += __shfl_xor(s,8); ss += __shfl_xor(ss,8);
    myS[i] = s; mySS[i] = ss;
    if (c == 0){ lnS[rl*2 + half] = s; lnSS[rl*2 + half] = ss; }
  }
  __syncthreads();
  #pragma unroll
  for (int i = 0; i < 4; ++i){
    int rl = m0 + q*4 + i, rg = r0 + rl;
    float sT  = myS[i]  + lnS[rl*2 + (half^1)];
    float ssT = mySS[i] + lnSS[rl*2 + (half^1)];
    float mean = sT * 0.0078125f;
    float var  = ssT * 0.0078125f - mean*mean;
    float rs   = rsqrtf(var + 1e-5f);
    if (rg < nrows){
      #pragma unroll
      for (int nt = 0; nt < 4; ++nt){
        int col = (ntb + nt)*16 + c;
        xvf[(size_t)rg*HD + col] = (vals[i][nt]-mean)*rs*gl[col] + bl[col];
      }
    }
  }
}

// ---------------- edge encoder v2: 512 threads, 8 waves nt-split, LN half-exchange ------
// writes xeb in RECEIVER-SORTED order (row j = edge perm[j])
__global__ __launch_bounds__(512, 4) void enc_edge(
    const float* ea, const int* perm, const float* W1, const float* b1,
    const unsigned short* pkW2, const float* b2,
    const float* gl, const float* bl, unsigned short* xeb)
{
  __shared__ float inb[64*4];
  __shared__ __align__(16) short Hh[64*SA];
  __shared__ __align__(16) short Hl[64*SA];
  __shared__ float lnS[128], lnSS[128];        // [row*2 + half]
  int tid = threadIdx.x, r0 = blockIdx.x * 64;
  if (tid < 256){
    int rr = tid >> 2, k = tid & 3;
    int pe = perm[r0 + rr];
    inb[tid] = ea[(size_t)pe*4 + k];
  }
  __syncthreads();
  {
    int cc = tid & 127;
    float w0 = W1[0*HD+cc], w1 = W1[1*HD+cc], w2 = W1[2*HD+cc], w3 = W1[3*HD+cc];
    float bb = b1[cc];
    for (int it = 0; it < 16; ++it){
      int rr = it*4 + (tid >> 7);
      float a = bb + inb[rr*4+0]*w0 + inb[rr*4+1]*w1 + inb[rr*4+2]*w2 + inb[rr*4+3]*w3;
      float h = fmaxf(a, 0.f);
      unsigned short hh = f2bf(h);
      Hh[rr*SA + cc] = (short)hh;
      Hl[rr*SA + cc] = (short)f2bf(h - bf2f(hh));
    }
  }
  __syncthreads();
  int lane = tid & 63, wq = tid >> 6, q = lane >> 4, c = lane & 15;
  int m0 = (wq & 3) * 16, ntb = (wq >> 2) * 4, half = wq >> 2;
  facc a2[4];
  #pragma unroll
  for (int nt = 0; nt < 4; ++nt) a2[nt] = (facc){0.f,0.f,0.f,0.f};
  gemm_tile_h(Hh, pkW2,         m0, ntb, lane, a2);
  gemm_tile_h(Hl, pkW2,         m0, ntb, lane, a2);
  gemm_tile_h(Hh, pkW2 + 16384, m0, ntb, lane, a2);
  float vals[4][4], myS[4], mySS[4];
  #pragma unroll
  for (int i = 0; i < 4; ++i){
    int rl = m0 + q*4 + i;
    float s = 0.f, ss = 0.f;
    #pragma unroll
    for (int nt = 0; nt < 4; ++nt){
      float v = a2[nt][i] + b2[(ntb + nt)*16 + c];
      vals[i][nt] = v; s += v; ss += v*v;
    }
    s += __shfl_xor(s,1); ss += __shfl_xor(ss,1);
    s += __shfl_xor(s,2); ss += __shfl_xor(ss,2);
    s += __shfl_xor(s,4); ss += __shfl_xor(ss,4);
    s += __shfl_xor(s,8); ss += __shfl_xor(ss,8);
    myS[i] = s; mySS[i] = ss;
    if (c == 0){ lnS[rl*2 + half] = s; lnSS[rl*2 + half] = ss; }
  }
  __syncthreads();
  #pragma unroll
  for (int i = 0; i < 4; ++i){
    int rl = m0 + q*4 + i, rg = r0 + rl;
    float sT  = myS[i]  + lnS[rl*2 + (half^1)];
    float ssT = mySS[i] + lnSS[rl*2 + (half^1)];
    float mean = sT * 0.0078125f;
    float var  = ssT * 0.0078125f - mean*mean;
    float rs   = rsqrtf(var + 1e-5f);
    #pragma unroll
    for (int nt = 0; nt < 4; ++nt){
      int col = (ntb + nt)*16 + c;
      xeb[(size_t)rg*HD + col] = f2bf((vals[i][nt]-mean)*rs*gl[col] + bl[col]);
    }
  }
}

// ---- P,Q = x_v @ EW1[0:128], @ EW1[128:256] — 8 waves, nt-split halves (layer 0 only) ----
__global__ __launch_bounds__(512, 4) void pq_kernel(
    const float* xvf, const unsigned short* pkA, const unsigned short* pkB,
    unsigned short* P, unsigned short* Q, int nrows)
{
  __shared__ __align__(16) short Ah[64*SA];
  __shared__ __align__(16) short Al[64*SA];
  int tid = threadIdx.x, r0 = blockIdx.x * 64;
  for (int j = tid; j < 1024; j += 512){
    int rr = j >> 4, ch = j & 15, rg = r0 + rr;
    float v[8];
    if (rg < nrows){
      f4v a = *(const f4v*)(xvf + (size_t)rg*HD + ch*8);
      f4v b = *(const f4v*)(xvf + (size_t)rg*HD + ch*8 + 4);
      v[0]=a[0];v[1]=a[1];v[2]=a[2];v[3]=a[3];v[4]=b[0];v[5]=b[1];v[6]=b[2];v[7]=b[3];
    } else {
      #pragma unroll
      for (int k = 0; k < 8; ++k) v[k] = 0.f;
    }
    short* dh = Ah + rr*SA + ch*8;
    short* dl = Al + rr*SA + ch*8;
    #pragma unroll
    for (int k = 0; k < 8; ++k){
      unsigned short h = f2bf(v[k]);
      dh[k] = (short)h; dl[k] = (short)f2bf(v[k] - bf2f(h));
    }
  }
  __syncthreads();
  int lane = tid & 63, wq = tid >> 6, q = lane >> 4, c = lane & 15;
  int m0 = (wq & 3) * 16, ntb = (wq >> 2) * 4;
  facc ap[4], aq[4];
  #pragma unroll
  for (int nt = 0; nt < 4; ++nt){ ap[nt] = (facc){0.f,0.f,0.f,0.f}; aq[nt] = (facc){0.f,0.f,0.f,0.f}; }
  gemm_tile_h(Ah, pkA,         m0, ntb, lane, ap);
  gemm_tile_h(Al, pkA,         m0, ntb, lane, ap);
  gemm_tile_h(Ah, pkA + 16384, m0, ntb, lane, ap);
  gemm_tile_h(Ah, pkB,         m0, ntb, lane, aq);
  gemm_tile_h(Al, pkB,         m0, ntb, lane, aq);
  gemm_tile_h(Ah, pkB + 16384, m0, ntb, lane, aq);
  #pragma unroll
  for (int i = 0; i < 4; ++i){
    int rl = m0 + q*4 + i, rg = r0 + rl;
    if (rg < nrows){
      s4v pv, qv;
      #pragma unroll
      for (int nt = 0; nt < 4; ++nt){
        pv[nt] = (short)f2bf(ap[nt][i]);
        qv[nt] = (short)f2bf(aq[nt][i]);
      }
      *(s4v*)(P + (size_t)rg*HD + c*8 + ntb) = pv;   // [row][c][nt] fragment layout
      *(s4v*)(Q + (size_t)rg*HD + c*8 + ntb) = qv;
    }
  }
}

// ---------------- edge update v9: 64 edges/block, 4 waves of 32 rows x 64 cols ------------
// ---------------- (gemm_tile_h2: each B frag feeds 2 MFMAs -> B L2-traffic halved) --------
__global__ __launch_bounds__(256, 3) void edge_kernel(
    unsigned short* xeb, const int* ssid, const int* srid,
    const unsigned short* P, const unsigned short* Q, const float* cbe,
    const unsigned short* pkW1c, const unsigned short* pkW2,
    const float* Eb2, const float* Eg, const float* Ebt)
{
  __shared__ __align__(16) short Ab[64*SA];    // becomes Hh after gemm1
  __shared__ __align__(16) short Hl[64*SA];
  __shared__ float lnS[128], lnSS[128];        // [row*2 + half]
  int tid = threadIdx.x, e0 = blockIdx.x * 64;
  int lane = tid & 63, wq = tid >> 6, q = lane >> 4, c = lane & 15;
  int m0 = (wq & 1) * 32, ntb = (wq >> 1) * 4, half = wq >> 1;

  // early: sender/receiver ids (L1-broadcast) + P/Q gathers for this thread's 8 rows,
  // issued BEFORE the staging barrier so latency hides under Ab staging.
  float pg[2][4][4];
  {
    float cb[4];
    #pragma unroll
    for (int nt = 0; nt < 4; ++nt) cb[nt] = cbe[(ntb + nt)*16 + c];
    #pragma unroll
    for (int rs = 0; rs < 2; ++rs){
      #pragma unroll
      for (int i = 0; i < 4; ++i){
        int rl = m0 + rs*16 + q*4 + i;
        int sid = ssid[e0 + rl], rid = srid[e0 + rl];
        s4v ps = *(const s4v*)(P + (size_t)sid*HD + c*8 + ntb);
        s4v qr = *(const s4v*)(Q + (size_t)rid*HD + c*8 + ntb);
        #pragma unroll
        for (int nt = 0; nt < 4; ++nt)
          pg[rs][i][nt] = bf2f((unsigned short)ps[nt]) + bf2f((unsigned short)qr[nt]) + cb[nt];
      }
    }
  }

  for (int j = tid; j < 1024; j += 256){
    int rr = j >> 4, ch = j & 15;
    *(bfrag*)(Ab + rr*SA + ch*8) = *(const bfrag*)(xeb + (size_t)(e0+rr)*HD + ch*8);
  }
  __syncthreads();

  // residual (bf16) for this thread's 8 rows x 4-col quadrant, packed 2 per u32 (16 VGPRs)
  unsigned int rres[2][4][2];
  #pragma unroll
  for (int rs = 0; rs < 2; ++rs){
    #pragma unroll
    for (int i = 0; i < 4; ++i){
      int rl = m0 + rs*16 + q*4 + i;
      #pragma unroll
      for (int p2 = 0; p2 < 2; ++p2){
        unsigned short a0 = (unsigned short)Ab[rl*SA + (ntb + 2*p2    )*16 + c];
        unsigned short a1 = (unsigned short)Ab[rl*SA + (ntb + 2*p2 + 1)*16 + c];
        rres[rs][i][p2] = ((unsigned int)a1 << 16) | a0;
      }
    }
  }
  facc acc0[4], acc1[4];
  #pragma unroll
  for (int nt = 0; nt < 4; ++nt){ acc0[nt] = (facc){0.f,0.f,0.f,0.f}; acc1[nt] = (facc){0.f,0.f,0.f,0.f}; }
  gemm_tile_h2(Ab, pkW1c,         m0, ntb, lane, acc0, acc1);   // xe exact bf16 -> 2 products
  gemm_tile_h2(Ab, pkW1c + 16384, m0, ntb, lane, acc0, acc1);
  __syncthreads();   // all Ab reads (gemm1 A-frags + rres) complete before overwrite
  #pragma unroll
  for (int rs = 0; rs < 2; ++rs){
    #pragma unroll
    for (int i = 0; i < 4; ++i){
      int rl = m0 + rs*16 + q*4 + i;
      #pragma unroll
      for (int nt = 0; nt < 4; ++nt){
        int col = (ntb + nt)*16 + c;
        float av = rs ? acc1[nt][i] : acc0[nt][i];
        float h = fmaxf(av + pg[rs][i][nt], 0.f);
        unsigned short hh = f2bf(h);
        Ab[rl*SA + col] = (short)hh;           // Hh in-place
        Hl[rl*SA + col] = (short)f2bf(h - bf2f(hh));
      }
    }
  }
  __syncthreads();
  facc a20[4], a21[4];
  #pragma unroll
  for (int nt = 0; nt < 4; ++nt){ a20[nt] = (facc){0.f,0.f,0.f,0.f}; a21[nt] = (facc){0.f,0.f,0.f,0.f}; }
  gemm_tile_h2(Ab, pkW2,         m0, ntb, lane, a20, a21);
  gemm_tile_h2(Hl, pkW2,         m0, ntb, lane, a20, a21);
  gemm_tile_h2(Ab, pkW2 + 16384, m0, ntb, lane, a20, a21);
  // ---- LN: 64-col partials per row, exchanged across the col-half wave pair via LDS ----
  float vals[2][4][4], myS[2][4], mySS[2][4];
  #pragma unroll
  for (int rs = 0; rs < 2; ++rs){
    #pragma unroll
    for (int i = 0; i < 4; ++i){
      int rl = m0 + rs*16 + q*4 + i;
      float s = 0.f, ss = 0.f;
      #pragma unroll
      for (int nt = 0; nt < 4; ++nt){
        float v = (rs ? a21[nt][i] : a20[nt][i]) + Eb2[(ntb + nt)*16 + c];
        vals[rs][i][nt] = v; s += v; ss += v*v;
      }
      s += __shfl_xor(s,1); ss += __shfl_xor(ss,1);
      s += __shfl_xor(s,2); ss += __shfl_xor(ss,2);
      s += __shfl_xor(s,4); ss += __shfl_xor(ss,4);
      s += __shfl_xor(s,8); ss += __shfl_xor(ss,8);
      myS[rs][i] = s; mySS[rs][i] = ss;
      if (c == 0){ lnS[rl*2 + half] = s; lnSS[rl*2 + half] = ss; }
    }
  }
  __syncthreads();
  #pragma unroll
  for (int rs = 0; rs < 2; ++rs){
    #pragma unroll
    for (int i = 0; i < 4; ++i){
      int rl = m0 + rs*16 + q*4 + i, eg = e0 + rl;
      float sT  = myS[rs][i]  + lnS[rl*2 + (half^1)];
      float ssT = mySS[rs][i] + lnSS[rl*2 + (half^1)];
      float mean = sT * 0.0078125f;
      float var  = ssT * 0.0078125f - mean*mean;
      float rs2  = rsqrtf(var + 1e-5f);
      #pragma unroll
      for (int nt = 0; nt < 4; ++nt){
        int col = (ntb + nt)*16 + c;
        float o = (vals[rs][i][nt]-mean)*rs2*Eg[col] + Ebt[col];
        float rv = bf2f((unsigned short)(rres[rs][i][nt >> 1] >> ((nt & 1)*16)));
        xeb[(size_t)eg*HD + col] = f2bf(rv + o);
      }
    }
  }
}

// ---------------- node update v6: 32 nodes/block, 4 waves (16x64 half-tile each), -------
// ---------------- fused aggregation (8 nodes/wave) + PQ tail; 625 blocks, ~36KB LDS -----
__global__ __launch_bounds__(256, 4) void node_kernel(
    float* xvf, const unsigned short* xeb, const int* base, const float* cbv,
    const unsigned short* pkW1a, const unsigned short* pkW1b, const unsigned short* pkW2,
    const float* Vb2, const float* Vg, const float* Vbt,
    float* xv_sum, float* xes, int do_xes,
    const unsigned short* pkAn, const unsigned short* pkBn,
    unsigned short* P, unsigned short* Q, int do_pq, int nrows)
{
  __shared__ __align__(16) short Avh[32*SA];   // reused as Hh after MLP1
  __shared__ __align__(16) short Avl[32*SA];   // reused as Hl
  __shared__ __align__(16) short Agh[32*SA];   // aggr; reused as xv_new-hi for PQ tail
  __shared__ __align__(16) short Agl[32*SA];   // aggr-lo; reused as xv_new-lo
  __shared__ float red[128];
  __shared__ float lnS[64], lnSS[64];          // [row*2 + half]
  int tid = threadIdx.x, r0 = blockIdx.x * 32;
  int lane = tid & 63, wq = tid >> 6;          // 4 waves
  if (tid < 128) red[tid] = 0.f;
  __syncthreads();   // red init visible before aggregation atomics
  // ---- stage x_v (hi/lo split): 32 rows x 16 chunks = 512 jobs ----
  for (int j = tid; j < 512; j += 256){
    int rr = j >> 4, ch = j & 15, rg = r0 + rr;
    float v[8];
    if (rg < nrows){
      f4v a = *(const f4v*)(xvf + (size_t)rg*HD + ch*8);
      f4v b = *(const f4v*)(xvf + (size_t)rg*HD + ch*8 + 4);
      v[0]=a[0];v[1]=a[1];v[2]=a[2];v[3]=a[3];v[4]=b[0];v[5]=b[1];v[6]=b[2];v[7]=b[3];
    } else {
      #pragma unroll
      for (int k = 0; k < 8; ++k) v[k] = 0.f;
    }
    short *dvh = Avh + rr*SA + ch*8, *dvl = Avl + rr*SA + ch*8;
    #pragma unroll
    for (int k = 0; k < 8; ++k){
      unsigned short h1 = f2bf(v[k]);
      dvh[k] = (short)h1; dvl[k] = (short)f2bf(v[k] - bf2f(h1));
    }
  }
  // ---- fused aggregation: wave wq sums nodes r0+wq*8 .. +7; lane covers cols 2l,2l+1 ----
  float xp0 = 0.f, xp1 = 0.f;
  for (int j = 0; j < 8; ++j){
    int rl = wq*8 + j, rg = r0 + rl;
    float s0 = 0.f, s1 = 0.f;
    if (rg < nrows){
      int b0 = base[rg], b1 = base[rg + 1];
      int e = b0;
      for (; e + 1 < b1; e += 2){
        unsigned int u0 = *(const unsigned int*)(xeb + (size_t)e*HD + lane*2);
        unsigned int u1 = *(const unsigned int*)(xeb + (size_t)(e+1)*HD + lane*2);
        s0 += bf2f((unsigned short)(u0 & 0xffffu)) + bf2f((unsigned short)(u1 & 0xffffu));
        s1 += bf2f((unsigned short)(u0 >> 16))     + bf2f((unsigned short)(u1 >> 16));
      }
      if (e < b1){
        unsigned int u0 = *(const unsigned int*)(xeb + (size_t)e*HD + lane*2);
        s0 += bf2f((unsigned short)(u0 & 0xffffu));
        s1 += bf2f((unsigned short)(u0 >> 16));
      }
    }
    unsigned short h0 = f2bf(s0), h1 = f2bf(s1);
    unsigned short l0 = f2bf(s0 - bf2f(h0)), l1 = f2bf(s1 - bf2f(h1));
    *(unsigned int*)(Agh + rl*SA + 2*lane) = ((unsigned int)h1 << 16) | h0;
    *(unsigned int*)(Agl + rl*SA + 2*lane) = ((unsigned int)l1 << 16) | l0;
    xp0 += s0; xp1 += s1;
  }
  if (do_xes){
    atomicAdd(&red[lane*2],     xp0);
    atomicAdd(&red[lane*2 + 1], xp1);
  }
  __syncthreads();
  if (do_xes && tid < 128) atomicAdd(&xes[tid], red[tid]);
  int q = lane >> 4, c = lane & 15;
  int m0 = (wq & 1) * 16, ntb = (wq >> 1) * 4, half = wq >> 1;
  facc acc[4];
  #pragma unroll
  for (int nt = 0; nt < 4; ++nt) acc[nt] = (facc){0.f,0.f,0.f,0.f};
  gemm_tile_h(Avh, pkW1a,         m0, ntb, lane, acc);
  gemm_tile_h(Avl, pkW1a,         m0, ntb, lane, acc);
  gemm_tile_h(Avh, pkW1a + 16384, m0, ntb, lane, acc);
  gemm_tile_h(Agh, pkW1b,         m0, ntb, lane, acc);
  gemm_tile_h(Agl, pkW1b,         m0, ntb, lane, acc);
  gemm_tile_h(Agh, pkW1b + 16384, m0, ntb, lane, acc);
  __syncthreads();   // everyone done reading Av/Ag planes before overwrite
  #pragma unroll
  for (int i = 0; i < 4; ++i){
    int rl = m0 + q*4 + i;
    #pragma unroll
    for (int nt = 0; nt < 4; ++nt){
      int col = (ntb + nt)*16 + c;
      float h = fmaxf(acc[nt][i] + cbv[col], 0.f);
      unsigned short hh = f2bf(h);
      Avh[rl*SA + col] = (short)hh;          // Hh
      Avl[rl*SA + col] = (short)f2bf(h - bf2f(hh)); // Hl
    }
  }
  __syncthreads();
  facc a2[4];
  #pragma unroll
  for (int nt = 0; nt < 4; ++nt) a2[nt] = (facc){0.f,0.f,0.f,0.f};
  gemm_tile_h(Avh, pkW2,         m0, ntb, lane, a2);
  gemm_tile_h(Avl, pkW2,         m0, ntb, lane, a2);
  gemm_tile_h(Avh, pkW2 + 16384, m0, ntb, lane, a2);
  // ---- LN: 64-col partials per wave, exchanged across the wave pair via LDS ----
  float vals[4][4], myS[4], mySS[4];
  #pragma unroll
  for (int i = 0; i < 4; ++i){
    int rl = m0 + q*4 + i;
    float s = 0.f, ss = 0.f;
    #pragma unroll
    for (int nt = 0; nt < 4; ++nt){
      float v = a2[nt][i] + Vb2[(ntb + nt)*16 + c];
      vals[i][nt] = v; s += v; ss += v*v;
    }
    s += __shfl_xor(s,1); ss += __shfl_xor(ss,1);
    s += __shfl_xor(s,2); ss += __shfl_xor(ss,2);
    s += __shfl_xor(s,4); ss += __shfl_xor(ss,4);
    s += __shfl_xor(s,8); ss += __shfl_xor(ss,8);
    myS[i] = s; mySS[i] = ss;
    if (c == 0){ lnS[rl*2 + half] = s; lnSS[rl*2 + half] = ss; }
  }
  __syncthreads();
  float csum[4] = {0.f,0.f,0.f,0.f};
  #pragma unroll
  for (int i = 0; i < 4; ++i){
    int rl = m0 + q*4 + i, rg = r0 + rl;
    float sT  = myS[i]  + lnS[rl*2 + (half^1)];
    float ssT = mySS[i] + lnSS[rl*2 + (half^1)];
    float mean = sT * 0.0078125f;
    float var  = ssT * 0.0078125f - mean*mean;
    float rs   = rsqrtf(var + 1e-5f);
    if (rg < nrows){
      #pragma unroll
      for (int nt = 0; nt < 4; ++nt){
        int col = (ntb + nt)*16 + c;
        float o = (vals[i][nt]-mean)*rs*Vg[col] + Vbt[col];
        size_t gi = (size_t)rg*HD + col;
        float nv = xvf[gi] + o;
        xvf[gi] = nv;
        csum[nt] += nv;
        if (do_pq){   // stage xv_new hi/lo into dead Ag tiles for the PQ tail
          unsigned short hh = f2bf(nv);
          Agh[rl*SA + col] = (short)hh;
          Agl[rl*SA + col] = (short)f2bf(nv - bf2f(hh));
        }
      }
    }
  }
  #pragma unroll
  for (int nt = 0; nt < 4; ++nt){
    float v = csum[nt]; v += __shfl_xor(v,16); v += __shfl_xor(v,32);
    if (q == 0) atomicAdd(&xv_sum[(ntb + nt)*16 + c], v);
  }
  // ---- PQ tail: P,Q for the NEXT layer from xv_new (tail rows stay zero from aggregation) ----
  if (do_pq){
    __syncthreads();   // all xv_new hi/lo writes visible
    facc ap[4], aq[4];
    #pragma unroll
    for (int nt = 0; nt < 4; ++nt){ ap[nt] = (facc){0.f,0.f,0.f,0.f}; aq[nt] = (facc){0.f,0.f,0.f,0.f}; }
    gemm_tile_h(Agh, pkAn,         m0, ntb, lane, ap);
    gemm_tile_h(Agl, pkAn,         m0, ntb, lane, ap);
    gemm_tile_h(Agh, pkAn + 16384, m0, ntb, lane, ap);
    gemm_tile_h(Agh, pkBn,         m0, ntb, lane, aq);
    gemm_tile_h(Agl, pkBn,         m0, ntb, lane, aq);
    gemm_tile_h(Agh, pkBn + 16384, m0, ntb, lane, aq);
    #pragma unroll
    for (int i = 0; i < 4; ++i){
      int rl = m0 + q*4 + i, rg = r0 + rl;
      if (rg < nrows){
        s4v pv, qv;
        #pragma unroll
        for (int nt = 0; nt < 4; ++nt){
          pv[nt] = (short)f2bf(ap[nt][i]);
          qv[nt] = (short)f2bf(aq[nt][i]);
        }
        *(s4v*)(P + (size_t)rg*HD + c*8 + ntb) = pv;
        *(s4v*)(Q + (size_t)rg*HD + c*8 + ntb) = qv;
      }
    }
  }
}

// ---------------- global-state update + next-layer bias fold (1024 threads, 8-way k-split) ----
__global__ __launch_bounds__(1024) void g_kernel(
    float* xvs, float* xes, float* g,
    const float* GW1, const float* Gb1, const float* GW2, const float* Gb2,
    const float* Gg, const float* Gbt,
    float* cbe, float* cbv,
    const float* EW1n, const float* Eb1n, const float* VW1n, const float* Vb1n)
{
  __shared__ float gin[384], h1[128], gn[128], red[4];
  __shared__ float partA[8][128], partB[8][128];
  int tid = threadIdx.x, t = tid & 127, kk = tid >> 7;   // kk in 0..7
  if (tid < 384) gin[tid] = (tid < 128) ? xvs[tid] : (tid < 256) ? xes[tid-128] : g[tid-256];
  __syncthreads();
  // MLP1: 384 = 8 x 48
  {
    float a = 0.f;
    for (int k = kk*48; k < kk*48 + 48; ++k) a += gin[k] * GW1[(size_t)k*HD + t];
    partA[kk][t] = a;
  }
  __syncthreads();
  if (kk == 0){
    float a = Gb1[t];
    #pragma unroll
    for (int i = 0; i < 8; ++i) a += partA[i][t];
    h1[t] = fmaxf(a, 0.f);
  }
  __syncthreads();
  // MLP2: 128 = 8 x 16
  {
    float o = 0.f;
    for (int k = kk*16; k < kk*16 + 16; ++k) o += h1[k] * GW2[(size_t)k*HD + t];
    partA[kk][t] = o;
  }
  __syncthreads();
  float oo = 0.f;
  if (kk == 0){
    oo = Gb2[t];
    #pragma unroll
    for (int i = 0; i < 8; ++i) oo += partA[i][t];
  }
  __syncthreads();
  if (tid < 128){
    float s = oo;
    #pragma unroll
    for (int d = 1; d < 64; d <<= 1) s += __shfl_xor(s, d);
    if ((tid & 63) == 0) red[tid >> 6] = s;
  }
  __syncthreads();
  float mean = (red[0] + red[1]) * 0.0078125f;
  if (tid < 128){
    float dd = oo - mean;
    float v = dd * dd;
    #pragma unroll
    for (int d = 1; d < 64; d <<= 1) v += __shfl_xor(v, d);
    if ((tid & 63) == 0) red[2 + (tid >> 6)] = v;
  }
  __syncthreads();
  if (tid < 128){
    float rs = rsqrtf((red[2] + red[3]) * 0.0078125f + 1e-5f);
    float gnv = g[tid] + (oo - mean)*rs*Gg[tid] + Gbt[tid];
    g[tid] = gnv; gn[tid] = gnv;
    xvs[tid] = 0.f; xes[tid] = 0.f;
  }
  __syncthreads();
  // bias fold for next layer: 128 = 8 x 16 per output
  {
    float ce = 0.f, cv = 0.f;
    for (int k = kk*16; k < kk*16 + 16; ++k){
      ce += gn[k] * EW1n[(size_t)k*HD + t];
      cv += gn[k] * VW1n[(size_t)k*HD + t];
    }
    partA[kk][t] = ce; partB[kk][t] = cv;
  }
  __syncthreads();
  if (kk == 0){
    float ce = Eb1n[t], cv = Vb1n[t];
    #pragma unroll
    for (int i = 0; i < 8; ++i){ ce += partA[i][t]; cv += partB[i][t]; }
    cbe[t] = ce; cbv[t] = cv;
  }
}

// ---------------- decoder: fp32 in, fp32 out ----------------
__global__ __launch_bounds__(256) void decoder_kernel(
    const float* xv, const float* c1w, const float* c1b,
    const float* c2w, const float* c2b, float* out)
{
  __shared__ float xl[4][128];
  __shared__ float hl[4][232];
  __shared__ float w1[120], b1[8], w2[80];
  __shared__ float b2s;
  int tid = threadIdx.x, nl = tid >> 6, t = tid & 63;
  int n = blockIdx.x * 4 + nl;
  if (tid < 120) w1[tid] = c1w[tid];
  else if (tid < 128) b1[tid - 120] = c1b[tid - 120];
  else if (tid < 208) w2[tid - 128] = c2w[tid - 128];
  else if (tid == 208) b2s = c2b[0];
  xl[nl][t]      = xv[(size_t)n*HD + t];
  xl[nl][t + 64] = xv[(size_t)n*HD + 64 + t];
  __syncthreads();
  for (int j = t; j < 232; j += 64){
    int ch = j / 29, pp = j % 29;
    float a = b1[ch];
    #pragma unroll
    for (int u = 0; u < 15; ++u) a += xl[nl][4*pp + u] * w1[ch*15 + u];
    hl[nl][j] = fmaxf(a, 0.f);
  }
  __syncthreads();
  if (t < 20){
    float o = b2s;
    #pragma unroll
    for (int ch = 0; ch < 8; ++ch)
      #pragma unroll
      for (int u = 0; u < 10; ++u)
        o += hl[nl][ch*29 + t + u] * w2[ch*10 + u];
    out[(size_t)n*20 + t] = o;
  }
}

extern "C" void kernel_launch(void* const* d_in, const int* in_sizes, int n_in,
                              void* d_out, int out_size, void* d_ws, size_t ws_size,
                              hipStream_t stream)
{
  const float* x    = (const float*)d_in[0];
  const float* ea   = (const float*)d_in[1];
  const int*   eidx = (const int*)d_in[2];
  const float* Wn1  = (const float*)d_in[3];  const float* bn1  = (const float*)d_in[4];
  const float* Wn2  = (const float*)d_in[5];  const float* bn2  = (const float*)d_in[6];
  const float* gnln = (const float*)d_in[7];  const float* bnln = (const float*)d_in[8];
  const float* We1  = (const float*)d_in[9];  const float* be1  = (const float*)d_in[10];
  const float* We2  = (const float*)d_in[11]; const float* be2  = (const float*)d_in[12];
  const float* geln = (const float*)d_in[13]; const float* beln = (const float*)d_in[14];
  const float* lEW1 = (const float*)d_in[15]; const float* lEb1 = (const float*)d_in[16];
  const float* lEW2 = (const float*)d_in[17]; const float* lEb2 = (const float*)d_in[18];
  const float* lEg  = (const float*)d_in[19]; const float* lEbt = (const float*)d_in[20];
  const float* lVW1 = (const float*)d_in[21]; const float* lVb1 = (const float*)d_in[22];
  const float* lVW2 = (const float*)d_in[23]; const float* lVb2 = (const float*)d_in[24];
  const float* lVg  = (const float*)d_in[25]; const float* lVbt = (const float*)d_in[26];
  const float* lGW1 = (const float*)d_in[27]; const float* lGb1 = (const float*)d_in[28];
  const float* lGW2 = (const float*)d_in[29]; const float* lGb2 = (const float*)d_in[30];
  const float* lGg  = (const float*)d_in[31]; const float* lGbt = (const float*)d_in[32];
  const float* c1w  = (const float*)d_in[33]; const float* c1b  = (const float*)d_in[34];
  const float* c2w  = (const float*)d_in[35]; const float* c2b  = (const float*)d_in[36];

  char* ws = (char*)d_ws;
  size_t off = 0;
  auto alloc = [&](size_t b){ size_t o = off; off += (b + 255) & ~(size_t)255; return o; };
  unsigned short* pk   = (unsigned short*)(ws + alloc((size_t)30*2*16384*2)); // 1.97 MB hi/lo planes
  float*          g    = (float*)(ws + alloc(512));
  float*          cbe  = (float*)(ws + alloc(512));
  float*          cbv  = (float*)(ws + alloc(512));
  float*          xvs  = (float*)(ws + alloc(512));
  float*          xes  = (float*)(ws + alloc(512));
  float*          xvf  = (float*)(ws + alloc((size_t)NN*HD*4));          // 10.24 MB
  unsigned short* P    = (unsigned short*)(ws + alloc((size_t)NN*HD*2)); //  5.12 MB
  unsigned short* Q    = (unsigned short*)(ws + alloc((size_t)NN*HD*2)); //  5.12 MB
  unsigned short* xeb  = (unsigned short*)(ws + alloc((size_t)NE*HD*2)); // 40.96 MB (sorted order)
  int*            cnt  = (int*)(ws + alloc((size_t)NN*4));
  int*            bse  = (int*)(ws + alloc((size_t)(NN+1)*4));
  int*            ofs  = (int*)(ws + alloc((size_t)NN*4));
  int*            perm = (int*)(ws + alloc((size_t)NE*4));
  int*            ssid = (int*)(ws + alloc((size_t)NE*4));
  int*            srid = (int*)(ws + alloc((size_t)NE*4));

  if (ws_size < off){
    sentinel_kernel<<<1, 32, 0, stream>>>((float*)d_out, 20000.f + (float)(ws_size >> 20));
    return;
  }

  auto slot = [&](int m){ return pk + (size_t)m * 32768; };  // hi at +0, lo at +16384

  pack_all<<<480, 256, 0, stream>>>(Wn2, We2, lEW1, lEW2, lVW1, lVW2, pk);
  init_small<<<1, 128, 0, stream>>>(g, cbe, cbv, xvs, xes, lEb1, lVb1);
  // counting sort of edges by receiver (once per launch)
  zero_cnt<<<(NN + 255)/256, 256, 0, stream>>>(cnt);
  hist_kernel<<<NE/256, 256, 0, stream>>>(eidx, cnt);
  scan_kernel<<<1, 1024, 0, stream>>>(cnt, bse, ofs);
  scatter_kernel<<<NE/256, 256, 0, stream>>>(eidx, ofs, perm, ssid, srid);

  enc_node<<<(NN + 63)/64, 512, 0, stream>>>(x, Wn1, bn1, slot(0), bn2, gnln, bnln, xvf, NN);
  enc_edge<<<NE/64, 512, 0, stream>>>(ea, perm, We1, be1, slot(1), be2, geln, beln, xeb);

  // P/Q for layer 0 (later layers produce P/Q in node_kernel's tail)
  pq_kernel<<<(NN + 63)/64, 512, 0, stream>>>(xvf, slot(2), slot(3), P, Q, NN);

  for (int l = 0; l < 4; ++l){
    int m = 2 + 7*l;
    edge_kernel<<<NE/64, 256, 0, stream>>>(xeb, ssid, srid, P, Q, cbe,
        slot(m+2), slot(m+3),
        lEb2 + (size_t)l*HD, lEg + (size_t)l*HD, lEbt + (size_t)l*HD);
    node_kernel<<<(NN + 31)/32, 256, 0, stream>>>(xvf, xeb, bse, cbv,
        slot(m+4), slot(m+5), slot(m+6),
        lVb2 + (size_t)l*HD, lVg + (size_t)l*HD, lVbt + (size_t)l*HD,
        xvs, xes, (l < 3) ? 1 : 0,
        slot(m+7), slot(m+8), P, Q, (l < 3) ? 1 : 0, NN);
    if (l < 3){
      g_kernel<<<1, 1024, 0, stream>>>(xvs, xes, g,
          lGW1 + (size_t)l*384*HD, lGb1 + (size_t)l*HD,
          lGW2 + (size_t)l*HD*HD, lGb2 + (size_t)l*HD,
          lGg + (size_t)l*HD, lGbt + (size_t)l*HD,
          cbe, cbv,
          lEW1 + ((size_t)(l+1)*512 + 384)*HD, lEb1 + (size_t)(l+1)*HD,
          lVW1 + ((size_t)(l+1)*384 + 256)*HD, lVb1 + (size_t)(l+1)*HD);
    }
  }
  decoder_kernel<<<NN/4, 256, 0, stream>>>(xvf, c1w, c1b, c2w, c2b, (float*)d_out);

  hipError_t e = hipGetLastError();
  if (e != hipSuccess){
    sentinel_kernel<<<1, 32, 0, stream>>>((float*)d_out, 10000.f + (float)e);
  }
  (void)in_sizes; (void)n_in; (void)out_size;
}

// Round 18
// 792.049 us; speedup vs baseline: 1.0210x; 1.0210x over previous
//
#include <hip/hip_runtime.h>

#define NN 20000
#define NE 160000
#define HD 128
#define SA 136   // LDS A-tile row stride (bf16 elems); 272B rows, 16B-aligned

typedef __attribute__((ext_vector_type(8))) short  bfrag;   // 8 bf16 = one MFMA A/B frag
typedef __attribute__((ext_vector_type(4))) short  s4v;     // half-frag (8B)
typedef __attribute__((ext_vector_type(4))) float  facc;    // MFMA C/D frag
typedef __attribute__((ext_vector_type(4))) float  f4v;

__device__ __forceinline__ float bf2f(unsigned short u){
  union { unsigned int i; float f; } v; v.i = ((unsigned int)u) << 16; return v.f;
}
__device__ __forceinline__ unsigned short f2bf(float f){
  union { float f; unsigned int i; } v; v.f = f;
  unsigned int r = v.i + 0x7fffu + ((v.i >> 16) & 1u);
  return (unsigned short)(r >> 16);
}

__global__ void sentinel_kernel(float* out, float code){
  if (threadIdx.x < 32) out[threadIdx.x] = code;
}

// A (LDS, [64][SA] bf16) @ B (global, fragment-packed 128x128 bf16) += acc[8]
// packed[((kt*8+nt)*64+lane)*8+j] = W[kt*32+(lane>>4)*8+j][nt*16+(lane&15)]
__device__ __forceinline__ void gemm_tile(const short* Ab,
                                          const unsigned short* pk,
                                          int m0, int lane, facc acc[8]){
  const int q = lane >> 4, c = lane & 15;
  #pragma unroll
  for (int kt = 0; kt < 4; ++kt){
    bfrag a = *(const bfrag*)(Ab + (m0 + c) * SA + kt * 32 + q * 8);
    const bfrag* bp = (const bfrag*)pk + kt * 512 + lane;
    #pragma unroll
    for (int nt = 0; nt < 8; ++nt){
      acc[nt] = __builtin_amdgcn_mfma_f32_16x16x32_bf16(a, bp[nt * 64], acc[nt], 0, 0, 0);
    }
  }
}

// nt-split half-tile: wave computes rows m0..m0+15 x cols [ntb*16, ntb*16+64).
// Per-acc accumulation order (kt outer, nt inner) identical to gemm_tile -> bitwise same.
__device__ __forceinline__ void gemm_tile_h(const short* Ab,
                                            const unsigned short* pk,
                                            int m0, int ntb, int lane, facc acc[4]){
  const int q = lane >> 4, c = lane & 15;
  #pragma unroll
  for (int kt = 0; kt < 4; ++kt){
    bfrag a = *(const bfrag*)(Ab + (m0 + c) * SA + kt * 32 + q * 8);
    const bfrag* bp = (const bfrag*)pk + kt * 512 + ntb * 64 + lane;
    #pragma unroll
    for (int nt = 0; nt < 4; ++nt){
      acc[nt] = __builtin_amdgcn_mfma_f32_16x16x32_bf16(a, bp[nt * 64], acc[nt], 0, 0, 0);
    }
  }
}

// 2-row-set variant: wave computes rows m0..m0+31 x cols [ntb*16, ntb*16+64).
// Each B fragment loaded ONCE feeds 2 MFMAs (row sets m0, m0+16) -> B L2-traffic halved.
// Per-acc order: acc0/acc1 each get one MFMA per kt in kt order -> bitwise identical
// to gemm_tile_h(m0) / gemm_tile_h(m0+16).
__device__ __forceinline__ void gemm_tile_h2(const short* Ab,
                                             const unsigned short* pk,
                                             int m0, int ntb, int lane,
                                             facc acc0[4], facc acc1[4]){
  const int q = lane >> 4, c = lane & 15;
  #pragma unroll
  for (int kt = 0; kt < 4; ++kt){
    bfrag a0 = *(const bfrag*)(Ab + (m0 +      c) * SA + kt * 32 + q * 8);
    bfrag a1 = *(const bfrag*)(Ab + (m0 + 16 + c) * SA + kt * 32 + q * 8);
    const bfrag* bp = (const bfrag*)pk + kt * 512 + ntb * 64 + lane;
    #pragma unroll
    for (int nt = 0; nt < 4; ++nt){
      bfrag b = bp[nt * 64];
      acc0[nt] = __builtin_amdgcn_mfma_f32_16x16x32_bf16(a0, b, acc0[nt], 0, 0, 0);
      acc1[nt] = __builtin_amdgcn_mfma_f32_16x16x32_bf16(a1, b, acc1[nt], 0, 0, 0);
    }
  }
}

// -------- pack 30 fp32 128x128 matrices -> hi/lo bf16 fragment planes (60 planes) --------
__global__ __launch_bounds__(256) void pack_all(
    const float* Wn2, const float* We2,
    const float* lEW1, const float* lEW2,
    const float* lVW1, const float* lVW2,
    unsigned short* packed)
{
  int job = blockIdx.x * 256 + threadIdx.x;   // 30 mats * 4096 (2 planes * 2048)
  int mat = job >> 12, r12 = job & 4095;
  int plane = r12 >> 11, r = r12 & 2047;
  int kt = r >> 9, nt = (r >> 6) & 7, lane = r & 63;
  const float* src;
  if (mat == 0) src = Wn2;
  else if (mat == 1) src = We2;
  else {
    int m2 = mat - 2, l = m2 / 7, t = m2 % 7;
    switch (t){
      case 0: src = lEW1 + ((size_t)l*512 +   0)*HD; break;   // P weights
      case 1: src = lEW1 + ((size_t)l*512 + 128)*HD; break;   // Q weights
      case 2: src = lEW1 + ((size_t)l*512 + 256)*HD; break;   // xe weights
      case 3: src = lEW2 + (size_t)l*HD*HD;          break;
      case 4: src = lVW1 + ((size_t)l*384 +   0)*HD; break;   // x_v weights
      case 5: src = lVW1 + ((size_t)l*384 + 128)*HD; break;   // aggr weights
      default: src = lVW2 + (size_t)l*HD*HD;         break;
    }
  }
  int krow = kt*32 + (lane>>4)*8, col = nt*16 + (lane&15);
  unsigned short v[8];
  #pragma unroll
  for (int j = 0; j < 8; ++j){
    float w = src[(size_t)(krow + j)*HD + col];
    unsigned short h = f2bf(w);
    v[j] = plane ? f2bf(w - bf2f(h)) : h;
  }
  unsigned short* dst = packed + ((size_t)mat*2 + plane)*16384
                               + ((size_t)(kt*8+nt)*64 + lane)*8;
  #pragma unroll
  for (int j = 0; j < 8; ++j) dst[j] = v[j];
}

// ---------------- init ----------------
__global__ __launch_bounds__(128) void init_small(
    float* g, float* cbe, float* cbv, float* xvs, float* xes,
    const float* Eb1_0, const float* Vb1_0)
{
  int t = threadIdx.x;
  g[t] = 0.f; xvs[t] = 0.f; xes[t] = 0.f;
  cbe[t] = Eb1_0[t]; cbv[t] = Vb1_0[t];
}

// ---------------- preprocessing: counting sort of edges by receiver ----------------
__global__ __launch_bounds__(256) void zero_cnt(int* cnt){
  int i = blockIdx.x * 256 + threadIdx.x;
  if (i < NN) cnt[i] = 0;
}
__global__ __launch_bounds__(256) void hist_kernel(const int* eidx, int* cnt){
  int e = blockIdx.x * 256 + threadIdx.x;
  atomicAdd(&cnt[eidx[NE + e]], 1);
}
// exclusive prefix sum over NN counts -> base[0..NN], plus mutable copy ofs
__global__ __launch_bounds__(1024) void scan_kernel(const int* cnt, int* base, int* ofs){
  __shared__ int wsum[16];
  int t = threadIdx.x, lane = t & 63;
  int vals[20]; int loc = 0;
  if (t < 1000){
    #pragma unroll
    for (int k = 0; k < 20; ++k){ vals[k] = cnt[t*20 + k]; loc += vals[k]; }
  }
  int inc = loc;
  #pragma unroll
  for (int d = 1; d < 64; d <<= 1){ int o = __shfl_up(inc, d); if (lane >= d) inc += o; }
  if (lane == 63) wsum[t >> 6] = inc;
  __syncthreads();
  if (t < 16){
    int v = wsum[t];
    #pragma unroll
    for (int d = 1; d < 16; d <<= 1){ int o = __shfl_up(v, d); if (t >= d) v += o; }
    wsum[t] = v;
  }
  __syncthreads();
  int woff = (t >= 64) ? wsum[(t >> 6) - 1] : 0;
  int run = woff + inc - loc;   // exclusive prefix for this thread's chunk
  if (t < 1000){
    #pragma unroll
    for (int k = 0; k < 20; ++k){ base[t*20 + k] = run; ofs[t*20 + k] = run; run += vals[k]; }
  }
  if (t == 0) base[NN] = NE;
}
__global__ __launch_bounds__(256) void scatter_kernel(const int* eidx, int* ofs,
                                                      int* perm, int* ssid, int* srid){
  int e = blockIdx.x * 256 + threadIdx.x;
  int s = eidx[e], r = eidx[NE + e];
  int pos = atomicAdd(&ofs[r], 1);
  perm[pos] = e; ssid[pos] = s; srid[pos] = r;
}

// ---------------- node encoder v2: 512 threads, 8 waves nt-split, LN half-exchange ------
__global__ __launch_bounds__(512, 4) void enc_node(
    const float* x, const float* W1, const float* b1,
    const unsigned short* pkW2, const float* b2,
    const float* gl, const float* bl, float* xvf, int nrows)
{
  __shared__ float inb[64*12];
  __shared__ __align__(16) short Hh[64*SA];
  __shared__ __align__(16) short Hl[64*SA];
  __shared__ float lnS[128], lnSS[128];        // [row*2 + half]
  int tid = threadIdx.x, r0 = blockIdx.x * 64;
  for (int j = tid; j < 64*12; j += 512){
    int rr = j / 12, k = j % 12, rg = r0 + rr;
    inb[j] = (rg < nrows) ? x[(size_t)rg*12 + k] : 0.f;
  }
  __syncthreads();
  {
    int cc = tid & 127;
    float w1c[12];
    #pragma unroll
    for (int k = 0; k < 12; ++k) w1c[k] = W1[k*HD + cc];
    float bb = b1[cc];
    for (int it = 0; it < 16; ++it){
      int rr = it*4 + (tid >> 7);
      float a = bb;
      #pragma unroll
      for (int k = 0; k < 12; ++k) a += inb[rr*12 + k] * w1c[k];
      float h = fmaxf(a, 0.f);
      unsigned short hh = f2bf(h);
      Hh[rr*SA + cc] = (short)hh;
      Hl[rr*SA + cc] = (short)f2bf(h - bf2f(hh));
    }
  }
  __syncthreads();
  int lane = tid & 63, wq = tid >> 6, q = lane >> 4, c = lane & 15;
  int m0 = (wq & 3) * 16, ntb = (wq >> 2) * 4, half = wq >> 2;
  facc a2[4];
  #pragma unroll
  for (int nt = 0; nt < 4; ++nt) a2[nt] = (facc){0.f,0.f,0.f,0.f};
  gemm_tile_h(Hh, pkW2,         m0, ntb, lane, a2);
  gemm_tile_h(Hl, pkW2,         m0, ntb, lane, a2);
  gemm_tile_h(Hh, pkW2 + 16384, m0, ntb, lane, a2);
  float vals[4][4], myS[4], mySS[4];
  #pragma unroll
  for (int i = 0; i < 4; ++i){
    int rl = m0 + q*4 + i;
    float s = 0.f, ss = 0.f;
    #pragma unroll
    for (int nt = 0; nt < 4; ++nt){
      float v = a2[nt][i] + b2[(ntb + nt)*16 + c];
      vals[i][nt] = v; s += v; ss += v*v;
    }
    s += __shfl_xor(s,1); ss += __shfl_xor(ss,1);
    s += __shfl_xor(s,2); ss += __shfl_xor(ss,2);
    s += __shfl_xor(s,4); ss += __shfl_xor(ss,4);
    s += __shfl_xor(s,8); ss += __shfl_xor(ss,8);
    myS[i] = s; mySS[i] = ss;
    if (c == 0){ lnS[rl*2 + half] = s; lnSS[rl*2 + half] = ss; }
  }
  __syncthreads();
  #pragma unroll
  for (int i = 0; i < 4; ++i){
    int rl = m0 + q*4 + i, rg = r0 + rl;
    float sT  = myS[i]  + lnS[rl*2 + (half^1)];
    float ssT = mySS[i] + lnSS[rl*2 + (half^1)];
    float mean = sT * 0.0078125f;
    float var  = ssT * 0.0078125f - mean*mean;
    float rs   = rsqrtf(var + 1e-5f);
    if (rg < nrows){
      #pragma unroll
      for (int nt = 0; nt < 4; ++nt){
        int col = (ntb + nt)*16 + c;
        xvf[(size_t)rg*HD + col] = (vals[i][nt]-mean)*rs*gl[col] + bl[col];
      }
    }
  }
}

// ---------------- edge encoder v2: 512 threads, 8 waves nt-split, LN half-exchange ------
// writes xeb in RECEIVER-SORTED order (row j = edge perm[j])
__global__ __launch_bounds__(512, 4) void enc_edge(
    const float* ea, const int* perm, const float* W1, const float* b1,
    const unsigned short* pkW2, const float* b2,
    const float* gl, const float* bl, unsigned short* xeb)
{
  __shared__ float inb[64*4];
  __shared__ __align__(16) short Hh[64*SA];
  __shared__ __align__(16) short Hl[64*SA];
  __shared__ float lnS[128], lnSS[128];        // [row*2 + half]
  int tid = threadIdx.x, r0 = blockIdx.x * 64;
  if (tid < 256){
    int rr = tid >> 2, k = tid & 3;
    int pe = perm[r0 + rr];
    inb[tid] = ea[(size_t)pe*4 + k];
  }
  __syncthreads();
  {
    int cc = tid & 127;
    float w0 = W1[0*HD+cc], w1 = W1[1*HD+cc], w2 = W1[2*HD+cc], w3 = W1[3*HD+cc];
    float bb = b1[cc];
    for (int it = 0; it < 16; ++it){
      int rr = it*4 + (tid >> 7);
      float a = bb + inb[rr*4+0]*w0 + inb[rr*4+1]*w1 + inb[rr*4+2]*w2 + inb[rr*4+3]*w3;
      float h = fmaxf(a, 0.f);
      unsigned short hh = f2bf(h);
      Hh[rr*SA + cc] = (short)hh;
      Hl[rr*SA + cc] = (short)f2bf(h - bf2f(hh));
    }
  }
  __syncthreads();
  int lane = tid & 63, wq = tid >> 6, q = lane >> 4, c = lane & 15;
  int m0 = (wq & 3) * 16, ntb = (wq >> 2) * 4, half = wq >> 2;
  facc a2[4];
  #pragma unroll
  for (int nt = 0; nt < 4; ++nt) a2[nt] = (facc){0.f,0.f,0.f,0.f};
  gemm_tile_h(Hh, pkW2,         m0, ntb, lane, a2);
  gemm_tile_h(Hl, pkW2,         m0, ntb, lane, a2);
  gemm_tile_h(Hh, pkW2 + 16384, m0, ntb, lane, a2);
  float vals[4][4], myS[4], mySS[4];
  #pragma unroll
  for (int i = 0; i < 4; ++i){
    int rl = m0 + q*4 + i;
    float s = 0.f, ss = 0.f;
    #pragma unroll
    for (int nt = 0; nt < 4; ++nt){
      float v = a2[nt][i] + b2[(ntb + nt)*16 + c];
      vals[i][nt] = v; s += v; ss += v*v;
    }
    s += __shfl_xor(s,1); ss += __shfl_xor(ss,1);
    s += __shfl_xor(s,2); ss += __shfl_xor(ss,2);
    s += __shfl_xor(s,4); ss += __shfl_xor(ss,4);
    s += __shfl_xor(s,8); ss += __shfl_xor(ss,8);
    myS[i] = s; mySS[i] = ss;
    if (c == 0){ lnS[rl*2 + half] = s; lnSS[rl*2 + half] = ss; }
  }
  __syncthreads();
  #pragma unroll
  for (int i = 0; i < 4; ++i){
    int rl = m0 + q*4 + i, rg = r0 + rl;
    float sT  = myS[i]  + lnS[rl*2 + (half^1)];
    float ssT = mySS[i] + lnSS[rl*2 + (half^1)];
    float mean = sT * 0.0078125f;
    float var  = ssT * 0.0078125f - mean*mean;
    float rs   = rsqrtf(var + 1e-5f);
    #pragma unroll
    for (int nt = 0; nt < 4; ++nt){
      int col = (ntb + nt)*16 + c;
      xeb[(size_t)rg*HD + col] = f2bf((vals[i][nt]-mean)*rs*gl[col] + bl[col]);
    }
  }
}

// ---- P,Q = x_v @ EW1[0:128], @ EW1[128:256] — 8 waves, nt-split halves (layer 0 only) ----
__global__ __launch_bounds__(512, 4) void pq_kernel(
    const float* xvf, const unsigned short* pkA, const unsigned short* pkB,
    unsigned short* P, unsigned short* Q, int nrows)
{
  __shared__ __align__(16) short Ah[64*SA];
  __shared__ __align__(16) short Al[64*SA];
  int tid = threadIdx.x, r0 = blockIdx.x * 64;
  for (int j = tid; j < 1024; j += 512){
    int rr = j >> 4, ch = j & 15, rg = r0 + rr;
    float v[8];
    if (rg < nrows){
      f4v a = *(const f4v*)(xvf + (size_t)rg*HD + ch*8);
      f4v b = *(const f4v*)(xvf + (size_t)rg*HD + ch*8 + 4);
      v[0]=a[0];v[1]=a[1];v[2]=a[2];v[3]=a[3];v[4]=b[0];v[5]=b[1];v[6]=b[2];v[7]=b[3];
    } else {
      #pragma unroll
      for (int k = 0; k < 8; ++k) v[k] = 0.f;
    }
    short* dh = Ah + rr*SA + ch*8;
    short* dl = Al + rr*SA + ch*8;
    #pragma unroll
    for (int k = 0; k < 8; ++k){
      unsigned short h = f2bf(v[k]);
      dh[k] = (short)h; dl[k] = (short)f2bf(v[k] - bf2f(h));
    }
  }
  __syncthreads();
  int lane = tid & 63, wq = tid >> 6, q = lane >> 4, c = lane & 15;
  int m0 = (wq & 3) * 16, ntb = (wq >> 2) * 4;
  facc ap[4], aq[4];
  #pragma unroll
  for (int nt = 0; nt < 4; ++nt){ ap[nt] = (facc){0.f,0.f,0.f,0.f}; aq[nt] = (facc){0.f,0.f,0.f,0.f}; }
  gemm_tile_h(Ah, pkA,         m0, ntb, lane, ap);
  gemm_tile_h(Al, pkA,         m0, ntb, lane, ap);
  gemm_tile_h(Ah, pkA + 16384, m0, ntb, lane, ap);
  gemm_tile_h(Ah, pkB,         m0, ntb, lane, aq);
  gemm_tile_h(Al, pkB,         m0, ntb, lane, aq);
  gemm_tile_h(Ah, pkB + 16384, m0, ntb, lane, aq);
  #pragma unroll
  for (int i = 0; i < 4; ++i){
    int rl = m0 + q*4 + i, rg = r0 + rl;
    if (rg < nrows){
      s4v pv, qv;
      #pragma unroll
      for (int nt = 0; nt < 4; ++nt){
        pv[nt] = (short)f2bf(ap[nt][i]);
        qv[nt] = (short)f2bf(aq[nt][i]);
      }
      *(s4v*)(P + (size_t)rg*HD + c*8 + ntb) = pv;   // [row][c][nt] fragment layout
      *(s4v*)(Q + (size_t)rg*HD + c*8 + ntb) = qv;
    }
  }
}

// ---------------- edge update v9: 64 edges/block, 4 waves of 32 rows x 64 cols ------------
// ---------------- (gemm_tile_h2: each B frag feeds 2 MFMAs -> B L2-traffic halved) --------
__global__ __launch_bounds__(256, 3) void edge_kernel(
    unsigned short* xeb, const int* ssid, const int* srid,
    const unsigned short* P, const unsigned short* Q, const float* cbe,
    const unsigned short* pkW1c, const unsigned short* pkW2,
    const float* Eb2, const float* Eg, const float* Ebt)
{
  __shared__ __align__(16) short Ab[64*SA];    // becomes Hh after gemm1
  __shared__ __align__(16) short Hl[64*SA];
  __shared__ float lnS[128], lnSS[128];        // [row*2 + half]
  int tid = threadIdx.x, e0 = blockIdx.x * 64;
  int lane = tid & 63, wq = tid >> 6, q = lane >> 4, c = lane & 15;
  int m0 = (wq & 1) * 32, ntb = (wq >> 1) * 4, half = wq >> 1;

  // early: sender/receiver ids (L1-broadcast) + P/Q gathers for this thread's 8 rows,
  // issued BEFORE the staging barrier so latency hides under Ab staging.
  float pg[2][4][4];
  {
    float cb[4];
    #pragma unroll
    for (int nt = 0; nt < 4; ++nt) cb[nt] = cbe[(ntb + nt)*16 + c];
    #pragma unroll
    for (int rs = 0; rs < 2; ++rs){
      #pragma unroll
      for (int i = 0; i < 4; ++i){
        int rl = m0 + rs*16 + q*4 + i;
        int sid = ssid[e0 + rl], rid = srid[e0 + rl];
        s4v ps = *(const s4v*)(P + (size_t)sid*HD + c*8 + ntb);
        s4v qr = *(const s4v*)(Q + (size_t)rid*HD + c*8 + ntb);
        #pragma unroll
        for (int nt = 0; nt < 4; ++nt)
          pg[rs][i][nt] = bf2f((unsigned short)ps[nt]) + bf2f((unsigned short)qr[nt]) + cb[nt];
      }
    }
  }

  for (int j = tid; j < 1024; j += 256){
    int rr = j >> 4, ch = j & 15;
    *(bfrag*)(Ab + rr*SA + ch*8) = *(const bfrag*)(xeb + (size_t)(e0+rr)*HD + ch*8);
  }
  __syncthreads();

  // residual (bf16) for this thread's 8 rows x 4-col quadrant, packed 2 per u32 (16 VGPRs)
  unsigned int rres[2][4][2];
  #pragma unroll
  for (int rs = 0; rs < 2; ++rs){
    #pragma unroll
    for (int i = 0; i < 4; ++i){
      int rl = m0 + rs*16 + q*4 + i;
      #pragma unroll
      for (int p2 = 0; p2 < 2; ++p2){
        unsigned short a0 = (unsigned short)Ab[rl*SA + (ntb + 2*p2    )*16 + c];
        unsigned short a1 = (unsigned short)Ab[rl*SA + (ntb + 2*p2 + 1)*16 + c];
        rres[rs][i][p2] = ((unsigned int)a1 << 16) | a0;
      }
    }
  }
  facc acc0[4], acc1[4];
  #pragma unroll
  for (int nt = 0; nt < 4; ++nt){ acc0[nt] = (facc){0.f,0.f,0.f,0.f}; acc1[nt] = (facc){0.f,0.f,0.f,0.f}; }
  gemm_tile_h2(Ab, pkW1c,         m0, ntb, lane, acc0, acc1);   // xe exact bf16 -> 2 products
  gemm_tile_h2(Ab, pkW1c + 16384, m0, ntb, lane, acc0, acc1);
  __syncthreads();   // all Ab reads (gemm1 A-frags + rres) complete before overwrite
  #pragma unroll
  for (int rs = 0; rs < 2; ++rs){
    #pragma unroll
    for (int i = 0; i < 4; ++i){
      int rl = m0 + rs*16 + q*4 + i;
      #pragma unroll
      for (int nt = 0; nt < 4; ++nt){
        int col = (ntb + nt)*16 + c;
        float av = rs ? acc1[nt][i] : acc0[nt][i];
        float h = fmaxf(av + pg[rs][i][nt], 0.f);
        unsigned short hh = f2bf(h);
        Ab[rl*SA + col] = (short)hh;           // Hh in-place
        Hl[rl*SA + col] = (short)f2bf(h - bf2f(hh));
      }
    }
  }
  __syncthreads();
  facc a20[4], a21[4];
  #pragma unroll
  for (int nt = 0; nt < 4; ++nt){ a20[nt] = (facc){0.f,0.f,0.f,0.f}; a21[nt] = (facc){0.f,0.f,0.f,0.f}; }
  gemm_tile_h2(Ab, pkW2,         m0, ntb, lane, a20, a21);
  gemm_tile_h2(Hl, pkW2,         m0, ntb, lane, a20, a21);
  gemm_tile_h2(Ab, pkW2 + 16384, m0, ntb, lane, a20, a21);
  // ---- LN: 64-col partials per row, exchanged across the col-half wave pair via LDS ----
  float vals[2][4][4], myS[2][4], mySS[2][4];
  #pragma unroll
  for (int rs = 0; rs < 2; ++rs){
    #pragma unroll
    for (int i = 0; i < 4; ++i){
      int rl = m0 + rs*16 + q*4 + i;
      float s = 0.f, ss = 0.f;
      #pragma unroll
      for (int nt = 0; nt < 4; ++nt){
        float v = (rs ? a21[nt][i] : a20[nt][i]) + Eb2[(ntb + nt)*16 + c];
        vals[rs][i][nt] = v; s += v; ss += v*v;
      }
      s += __shfl_xor(s,1); ss += __shfl_xor(ss,1);
      s += __shfl_xor(s,2); ss += __shfl_xor(ss,2);
      s += __shfl_xor(s,4); ss += __shfl_xor(ss,4);
      s += __shfl_xor(s,8); ss += __shfl_xor(ss,8);
      myS[rs][i] = s; mySS[rs][i] = ss;
      if (c == 0){ lnS[rl*2 + half] = s; lnSS[rl*2 + half] = ss; }
    }
  }
  __syncthreads();
  #pragma unroll
  for (int rs = 0; rs < 2; ++rs){
    #pragma unroll
    for (int i = 0; i < 4; ++i){
      int rl = m0 + rs*16 + q*4 + i, eg = e0 + rl;
      float sT  = myS[rs][i]  + lnS[rl*2 + (half^1)];
      float ssT = mySS[rs][i] + lnSS[rl*2 + (half^1)];
      float mean = sT * 0.0078125f;
      float var  = ssT * 0.0078125f - mean*mean;
      float rs2  = rsqrtf(var + 1e-5f);
      #pragma unroll
      for (int nt = 0; nt < 4; ++nt){
        int col = (ntb + nt)*16 + c;
        float o = (vals[rs][i][nt]-mean)*rs2*Eg[col] + Ebt[col];
        float rv = bf2f((unsigned short)(rres[rs][i][nt >> 1] >> ((nt & 1)*16)));
        xeb[(size_t)eg*HD + col] = f2bf(rv + o);
      }
    }
  }
}

// ---------------- node update v7: 32 nodes/block, 4 waves; aggregation with 8-wide ------
// ---------------- load batching (bitwise-identical pairwise sum order) + PQ tail --------
__global__ __launch_bounds__(256, 4) void node_kernel(
    float* xvf, const unsigned short* xeb, const int* base, const float* cbv,
    const unsigned short* pkW1a, const unsigned short* pkW1b, const unsigned short* pkW2,
    const float* Vb2, const float* Vg, const float* Vbt,
    float* xv_sum, float* xes, int do_xes,
    const unsigned short* pkAn, const unsigned short* pkBn,
    unsigned short* P, unsigned short* Q, int do_pq, int nrows)
{
  __shared__ __align__(16) short Avh[32*SA];   // reused as Hh after MLP1
  __shared__ __align__(16) short Avl[32*SA];   // reused as Hl
  __shared__ __align__(16) short Agh[32*SA];   // aggr; reused as xv_new-hi for PQ tail
  __shared__ __align__(16) short Agl[32*SA];   // aggr-lo; reused as xv_new-lo
  __shared__ float red[128];
  __shared__ float lnS[64], lnSS[64];          // [row*2 + half]
  int tid = threadIdx.x, r0 = blockIdx.x * 32;
  int lane = tid & 63, wq = tid >> 6;          // 4 waves
  if (tid < 128) red[tid] = 0.f;
  __syncthreads();   // red init visible before aggregation atomics
  // ---- stage x_v (hi/lo split): 32 rows x 16 chunks = 512 jobs ----
  for (int j = tid; j < 512; j += 256){
    int rr = j >> 4, ch = j & 15, rg = r0 + rr;
    float v[8];
    if (rg < nrows){
      f4v a = *(const f4v*)(xvf + (size_t)rg*HD + ch*8);
      f4v b = *(const f4v*)(xvf + (size_t)rg*HD + ch*8 + 4);
      v[0]=a[0];v[1]=a[1];v[2]=a[2];v[3]=a[3];v[4]=b[0];v[5]=b[1];v[6]=b[2];v[7]=b[3];
    } else {
      #pragma unroll
      for (int k = 0; k < 8; ++k) v[k] = 0.f;
    }
    short *dvh = Avh + rr*SA + ch*8, *dvl = Avl + rr*SA + ch*8;
    #pragma unroll
    for (int k = 0; k < 8; ++k){
      unsigned short h1 = f2bf(v[k]);
      dvh[k] = (short)h1; dvl[k] = (short)f2bf(v[k] - bf2f(h1));
    }
  }
  // ---- fused aggregation: wave wq sums nodes r0+wq*8 .. +7; lane covers cols 2l,2l+1 ----
  // 8-wide load batching: 8 independent loads in flight; accumulation stays in the
  // exact pairwise order of the 2-wide loop -> bitwise identical sums.
  float xp0 = 0.f, xp1 = 0.f;
  for (int j = 0; j < 8; ++j){
    int rl = wq*8 + j, rg = r0 + rl;
    float s0 = 0.f, s1 = 0.f;
    if (rg < nrows){
      int b0 = base[rg], b1 = base[rg + 1];
      int e = b0;
      for (; e + 7 < b1; e += 8){
        unsigned int u[8];
        #pragma unroll
        for (int k = 0; k < 8; ++k)
          u[k] = *(const unsigned int*)(xeb + (size_t)(e+k)*HD + lane*2);
        #pragma unroll
        for (int k = 0; k < 8; k += 2){
          s0 += bf2f((unsigned short)(u[k] & 0xffffu)) + bf2f((unsigned short)(u[k+1] & 0xffffu));
          s1 += bf2f((unsigned short)(u[k] >> 16))     + bf2f((unsigned short)(u[k+1] >> 16));
        }
      }
      for (; e + 1 < b1; e += 2){
        unsigned int u0 = *(const unsigned int*)(xeb + (size_t)e*HD + lane*2);
        unsigned int u1 = *(const unsigned int*)(xeb + (size_t)(e+1)*HD + lane*2);
        s0 += bf2f((unsigned short)(u0 & 0xffffu)) + bf2f((unsigned short)(u1 & 0xffffu));
        s1 += bf2f((unsigned short)(u0 >> 16))     + bf2f((unsigned short)(u1 >> 16));
      }
      if (e < b1){
        unsigned int u0 = *(const unsigned int*)(xeb + (size_t)e*HD + lane*2);
        s0 += bf2f((unsigned short)(u0 & 0xffffu));
        s1 += bf2f((unsigned short)(u0 >> 16));
      }
    }
    unsigned short h0 = f2bf(s0), h1 = f2bf(s1);
    unsigned short l0 = f2bf(s0 - bf2f(h0)), l1 = f2bf(s1 - bf2f(h1));
    *(unsigned int*)(Agh + rl*SA + 2*lane) = ((unsigned int)h1 << 16) | h0;
    *(unsigned int*)(Agl + rl*SA + 2*lane) = ((unsigned int)l1 << 16) | l0;
    xp0 += s0; xp1 += s1;
  }
  if (do_xes){
    atomicAdd(&red[lane*2],     xp0);
    atomicAdd(&red[lane*2 + 1], xp1);
  }
  __syncthreads();
  if (do_xes && tid < 128) atomicAdd(&xes[tid], red[tid]);
  int q = lane >> 4, c = lane & 15;
  int m0 = (wq & 1) * 16, ntb = (wq >> 1) * 4, half = wq >> 1;
  facc acc[4];
  #pragma unroll
  for (int nt = 0; nt < 4; ++nt) acc[nt] = (facc){0.f,0.f,0.f,0.f};
  gemm_tile_h(Avh, pkW1a,         m0, ntb, lane, acc);
  gemm_tile_h(Avl, pkW1a,         m0, ntb, lane, acc);
  gemm_tile_h(Avh, pkW1a + 16384, m0, ntb, lane, acc);
  gemm_tile_h(Agh, pkW1b,         m0, ntb, lane, acc);
  gemm_tile_h(Agl, pkW1b,         m0, ntb, lane, acc);
  gemm_tile_h(Agh, pkW1b + 16384, m0, ntb, lane, acc);
  __syncthreads();   // everyone done reading Av/Ag planes before overwrite
  #pragma unroll
  for (int i = 0; i < 4; ++i){
    int rl = m0 + q*4 + i;
    #pragma unroll
    for (int nt = 0; nt < 4; ++nt){
      int col = (ntb + nt)*16 + c;
      float h = fmaxf(acc[nt][i] + cbv[col], 0.f);
      unsigned short hh = f2bf(h);
      Avh[rl*SA + col] = (short)hh;          // Hh
      Avl[rl*SA + col] = (short)f2bf(h - bf2f(hh)); // Hl
    }
  }
  __syncthreads();
  facc a2[4];
  #pragma unroll
  for (int nt = 0; nt < 4; ++nt) a2[nt] = (facc){0.f,0.f,0.f,0.f};
  gemm_tile_h(Avh, pkW2,         m0, ntb, lane, a2);
  gemm_tile_h(Avl, pkW2,         m0, ntb, lane, a2);
  gemm_tile_h(Avh, pkW2 + 16384, m0, ntb, lane, a2);
  // ---- LN: 64-col partials per wave, exchanged across the wave pair via LDS ----
  float vals[4][4], myS[4], mySS[4];
  #pragma unroll
  for (int i = 0; i < 4; ++i){
    int rl = m0 + q*4 + i;
    float s = 0.f, ss = 0.f;
    #pragma unroll
    for (int nt = 0; nt < 4; ++nt){
      float v = a2[nt][i] + Vb2[(ntb + nt)*16 + c];
      vals[i][nt] = v; s += v; ss += v*v;
    }
    s += __shfl_xor(s,1); ss += __shfl_xor(ss,1);
    s += __shfl_xor(s,2); ss += __shfl_xor(ss,2);
    s += __shfl_xor(s,4); ss += __shfl_xor(ss,4);
    s += __shfl_xor(s,8); ss += __shfl_xor(ss,8);
    myS[i] = s; mySS[i] = ss;
    if (c == 0){ lnS[rl*2 + half] = s; lnSS[rl*2 + half] = ss; }
  }
  __syncthreads();
  float csum[4] = {0.f,0.f,0.f,0.f};
  #pragma unroll
  for (int i = 0; i < 4; ++i){
    int rl = m0 + q*4 + i, rg = r0 + rl;
    float sT  = myS[i]  + lnS[rl*2 + (half^1)];
    float ssT = mySS[i] + lnSS[rl*2 + (half^1)];
    float mean = sT * 0.0078125f;
    float var  = ssT * 0.0078125f - mean*mean;
    float rs   = rsqrtf(var + 1e-5f);
    if (rg < nrows){
      #pragma unroll
      for (int nt = 0; nt < 4; ++nt){
        int col = (ntb + nt)*16 + c;
        float o = (vals[i][nt]-mean)*rs*Vg[col] + Vbt[col];
        size_t gi = (size_t)rg*HD + col;
        float nv = xvf[gi] + o;
        xvf[gi] = nv;
        csum[nt] += nv;
        if (do_pq){   // stage xv_new hi/lo into dead Ag tiles for the PQ tail
          unsigned short hh = f2bf(nv);
          Agh[rl*SA + col] = (short)hh;
          Agl[rl*SA + col] = (short)f2bf(nv - bf2f(hh));
        }
      }
    }
  }
  #pragma unroll
  for (int nt = 0; nt < 4; ++nt){
    float v = csum[nt]; v += __shfl_xor(v,16); v += __shfl_xor(v,32);
    if (q == 0) atomicAdd(&xv_sum[(ntb + nt)*16 + c], v);
  }
  // ---- PQ tail: P,Q for the NEXT layer from xv_new (tail rows stay zero from aggregation) ----
  if (do_pq){
    __syncthreads();   // all xv_new hi/lo writes visible
    facc ap[4], aq[4];
    #pragma unroll
    for (int nt = 0; nt < 4; ++nt){ ap[nt] = (facc){0.f,0.f,0.f,0.f}; aq[nt] = (facc){0.f,0.f,0.f,0.f}; }
    gemm_tile_h(Agh, pkAn,         m0, ntb, lane, ap);
    gemm_tile_h(Agl, pkAn,         m0, ntb, lane, ap);
    gemm_tile_h(Agh, pkAn + 16384, m0, ntb, lane, ap);
    gemm_tile_h(Agh, pkBn,         m0, ntb, lane, aq);
    gemm_tile_h(Agl, pkBn,         m0, ntb, lane, aq);
    gemm_tile_h(Agh, pkBn + 16384, m0, ntb, lane, aq);
    #pragma unroll
    for (int i = 0; i < 4; ++i){
      int rl = m0 + q*4 + i, rg = r0 + rl;
      if (rg < nrows){
        s4v pv, qv;
        #pragma unroll
        for (int nt = 0; nt < 4; ++nt){
          pv[nt] = (short)f2bf(ap[nt][i]);
          qv[nt] = (short)f2bf(aq[nt][i]);
        }
        *(s4v*)(P + (size_t)rg*HD + c*8 + ntb) = pv;
        *(s4v*)(Q + (size_t)rg*HD + c*8 + ntb) = qv;
      }
    }
  }
}

// ---------------- global-state update + next-layer bias fold (1024 threads, 8-way k-split) ----
__global__ __launch_bounds__(1024) void g_kernel(
    float* xvs, float* xes, float* g,
    const float* GW1, const float* Gb1, const float* GW2, const float* Gb2,
    const float* Gg, const float* Gbt,
    float* cbe, float* cbv,
    const float* EW1n, const float* Eb1n, const float* VW1n, const float* Vb1n)
{
  __shared__ float gin[384], h1[128], gn[128], red[4];
  __shared__ float partA[8][128], partB[8][128];
  int tid = threadIdx.x, t = tid & 127, kk = tid >> 7;   // kk in 0..7
  if (tid < 384) gin[tid] = (tid < 128) ? xvs[tid] : (tid < 256) ? xes[tid-128] : g[tid-256];
  __syncthreads();
  // MLP1: 384 = 8 x 48
  {
    float a = 0.f;
    for (int k = kk*48; k < kk*48 + 48; ++k) a += gin[k] * GW1[(size_t)k*HD + t];
    partA[kk][t] = a;
  }
  __syncthreads();
  if (kk == 0){
    float a = Gb1[t];
    #pragma unroll
    for (int i = 0; i < 8; ++i) a += partA[i][t];
    h1[t] = fmaxf(a, 0.f);
  }
  __syncthreads();
  // MLP2: 128 = 8 x 16
  {
    float o = 0.f;
    for (int k = kk*16; k < kk*16 + 16; ++k) o += h1[k] * GW2[(size_t)k*HD + t];
    partA[kk][t] = o;
  }
  __syncthreads();
  float oo = 0.f;
  if (kk == 0){
    oo = Gb2[t];
    #pragma unroll
    for (int i = 0; i < 8; ++i) oo += partA[i][t];
  }
  __syncthreads();
  if (tid < 128){
    float s = oo;
    #pragma unroll
    for (int d = 1; d < 64; d <<= 1) s += __shfl_xor(s, d);
    if ((tid & 63) == 0) red[tid >> 6] = s;
  }
  __syncthreads();
  float mean = (red[0] + red[1]) * 0.0078125f;
  if (tid < 128){
    float dd = oo - mean;
    float v = dd * dd;
    #pragma unroll
    for (int d = 1; d < 64; d <<= 1) v += __shfl_xor(v, d);
    if ((tid & 63) == 0) red[2 + (tid >> 6)] = v;
  }
  __syncthreads();
  if (tid < 128){
    float rs = rsqrtf((red[2] + red[3]) * 0.0078125f + 1e-5f);
    float gnv = g[tid] + (oo - mean)*rs*Gg[tid] + Gbt[tid];
    g[tid] = gnv; gn[tid] = gnv;
    xvs[tid] = 0.f; xes[tid] = 0.f;
  }
  __syncthreads();
  // bias fold for next layer: 128 = 8 x 16 per output
  {
    float ce = 0.f, cv = 0.f;
    for (int k = kk*16; k < kk*16 + 16; ++k){
      ce += gn[k] * EW1n[(size_t)k*HD + t];
      cv += gn[k] * VW1n[(size_t)k*HD + t];
    }
    partA[kk][t] = ce; partB[kk][t] = cv;
  }
  __syncthreads();
  if (kk == 0){
    float ce = Eb1n[t], cv = Vb1n[t];
    #pragma unroll
    for (int i = 0; i < 8; ++i){ ce += partA[i][t]; cv += partB[i][t]; }
    cbe[t] = ce; cbv[t] = cv;
  }
}

// ---------------- decoder: fp32 in, fp32 out ----------------
__global__ __launch_bounds__(256) void decoder_kernel(
    const float* xv, const float* c1w, const float* c1b,
    const float* c2w, const float* c2b, float* out)
{
  __shared__ float xl[4][128];
  __shared__ float hl[4][232];
  __shared__ float w1[120], b1[8], w2[80];
  __shared__ float b2s;
  int tid = threadIdx.x, nl = tid >> 6, t = tid & 63;
  int n = blockIdx.x * 4 + nl;
  if (tid < 120) w1[tid] = c1w[tid];
  else if (tid < 128) b1[tid - 120] = c1b[tid - 120];
  else if (tid < 208) w2[tid - 128] = c2w[tid - 128];
  else if (tid == 208) b2s = c2b[0];
  xl[nl][t]      = xv[(size_t)n*HD + t];
  xl[nl][t + 64] = xv[(size_t)n*HD + 64 + t];
  __syncthreads();
  for (int j = t; j < 232; j += 64){
    int ch = j / 29, pp = j % 29;
    float a = b1[ch];
    #pragma unroll
    for (int u = 0; u < 15; ++u) a += xl[nl][4*pp + u] * w1[ch*15 + u];
    hl[nl][j] = fmaxf(a, 0.f);
  }
  __syncthreads();
  if (t < 20){
    float o = b2s;
    #pragma unroll
    for (int ch = 0; ch < 8; ++ch)
      #pragma unroll
      for (int u = 0; u < 10; ++u)
        o += hl[nl][ch*29 + t + u] * w2[ch*10 + u];
    out[(size_t)n*20 + t] = o;
  }
}

extern "C" void kernel_launch(void* const* d_in, const int* in_sizes, int n_in,
                              void* d_out, int out_size, void* d_ws, size_t ws_size,
                              hipStream_t stream)
{
  const float* x    = (const float*)d_in[0];
  const float* ea   = (const float*)d_in[1];
  const int*   eidx = (const int*)d_in[2];
  const float* Wn1  = (const float*)d_in[3];  const float* bn1  = (const float*)d_in[4];
  const float* Wn2  = (const float*)d_in[5];  const float* bn2  = (const float*)d_in[6];
  const float* gnln = (const float*)d_in[7];  const float* bnln = (const float*)d_in[8];
  const float* We1  = (const float*)d_in[9];  const float* be1  = (const float*)d_in[10];
  const float* We2  = (const float*)d_in[11]; const float* be2  = (const float*)d_in[12];
  const float* geln = (const float*)d_in[13]; const float* beln = (const float*)d_in[14];
  const float* lEW1 = (const float*)d_in[15]; const float* lEb1 = (const float*)d_in[16];
  const float* lEW2 = (const float*)d_in[17]; const float* lEb2 = (const float*)d_in[18];
  const float* lEg  = (const float*)d_in[19]; const float* lEbt = (const float*)d_in[20];
  const float* lVW1 = (const float*)d_in[21]; const float* lVb1 = (const float*)d_in[22];
  const float* lVW2 = (const float*)d_in[23]; const float* lVb2 = (const float*)d_in[24];
  const float* lVg  = (const float*)d_in[25]; const float* lVbt = (const float*)d_in[26];
  const float* lGW1 = (const float*)d_in[27]; const float* lGb1 = (const float*)d_in[28];
  const float* lGW2 = (const float*)d_in[29]; const float* lGb2 = (const float*)d_in[30];
  const float* lGg  = (const float*)d_in[31]; const float* lGbt = (const float*)d_in[32];
  const float* c1w  = (const float*)d_in[33]; const float* c1b  = (const float*)d_in[34];
  const float* c2w  = (const float*)d_in[35]; const float* c2b  = (const float*)d_in[36];

  char* ws = (char*)d_ws;
  size_t off = 0;
  auto alloc = [&](size_t b){ size_t o = off; off += (b + 255) & ~(size_t)255; return o; };
  unsigned short* pk   = (unsigned short*)(ws + alloc((size_t)30*2*16384*2)); // 1.97 MB hi/lo planes
  float*          g    = (float*)(ws + alloc(512));
  float*          cbe  = (float*)(ws + alloc(512));
  float*          cbv  = (float*)(ws + alloc(512));
  float*          xvs  = (float*)(ws + alloc(512));
  float*          xes  = (float*)(ws + alloc(512));
  float*          xvf  = (float*)(ws + alloc((size_t)NN*HD*4));          // 10.24 MB
  unsigned short* P    = (unsigned short*)(ws + alloc((size_t)NN*HD*2)); //  5.12 MB
  unsigned short* Q    = (unsigned short*)(ws + alloc((size_t)NN*HD*2)); //  5.12 MB
  unsigned short* xeb  = (unsigned short*)(ws + alloc((size_t)NE*HD*2)); // 40.96 MB (sorted order)
  int*            cnt  = (int*)(ws + alloc((size_t)NN*4));
  int*            bse  = (int*)(ws + alloc((size_t)(NN+1)*4));
  int*            ofs  = (int*)(ws + alloc((size_t)NN*4));
  int*            perm = (int*)(ws + alloc((size_t)NE*4));
  int*            ssid = (int*)(ws + alloc((size_t)NE*4));
  int*            srid = (int*)(ws + alloc((size_t)NE*4));

  if (ws_size < off){
    sentinel_kernel<<<1, 32, 0, stream>>>((float*)d_out, 20000.f + (float)(ws_size >> 20));
    return;
  }

  auto slot = [&](int m){ return pk + (size_t)m * 32768; };  // hi at +0, lo at +16384

  pack_all<<<480, 256, 0, stream>>>(Wn2, We2, lEW1, lEW2, lVW1, lVW2, pk);
  init_small<<<1, 128, 0, stream>>>(g, cbe, cbv, xvs, xes, lEb1, lVb1);
  // counting sort of edges by receiver (once per launch)
  zero_cnt<<<(NN + 255)/256, 256, 0, stream>>>(cnt);
  hist_kernel<<<NE/256, 256, 0, stream>>>(eidx, cnt);
  scan_kernel<<<1, 1024, 0, stream>>>(cnt, bse, ofs);
  scatter_kernel<<<NE/256, 256, 0, stream>>>(eidx, ofs, perm, ssid, srid);

  enc_node<<<(NN + 63)/64, 512, 0, stream>>>(x, Wn1, bn1, slot(0), bn2, gnln, bnln, xvf, NN);
  enc_edge<<<NE/64, 512, 0, stream>>>(ea, perm, We1, be1, slot(1), be2, geln, beln, xeb);

  // P/Q for layer 0 (later layers produce P/Q in node_kernel's tail)
  pq_kernel<<<(NN + 63)/64, 512, 0, stream>>>(xvf, slot(2), slot(3), P, Q, NN);

  for (int l = 0; l < 4; ++l){
    int m = 2 + 7*l;
    edge_kernel<<<NE/64, 256, 0, stream>>>(xeb, ssid, srid, P, Q, cbe,
        slot(m+2), slot(m+3),
        lEb2 + (size_t)l*HD, lEg + (size_t)l*HD, lEbt + (size_t)l*HD);
    node_kernel<<<(NN + 31)/32, 256, 0, stream>>>(xvf, xeb, bse, cbv,
        slot(m+4), slot(m+5), slot(m+6),
        lVb2 + (size_t)l*HD, lVg + (size_t)l*HD, lVbt + (size_t)l*HD,
        xvs, xes, (l < 3) ? 1 : 0,
        slot(m+7), slot(m+8), P, Q, (l < 3) ? 1 : 0, NN);
    if (l < 3){
      g_kernel<<<1, 1024, 0, stream>>>(xvs, xes, g,
          lGW1 + (size_t)l*384*HD, lGb1 + (size_t)l*HD,
          lGW2 + (size_t)l*HD*HD, lGb2 + (size_t)l*HD,
          lGg + (size_t)l*HD, lGbt + (size_t)l*HD,
          cbe, cbv,
          lEW1 + ((size_t)(l+1)*512 + 384)*HD, lEb1 + (size_t)(l+1)*HD,
          lVW1 + ((size_t)(l+1)*384 + 256)*HD, lVb1 + (size_t)(l+1)*HD);
    }
  }
  decoder_kernel<<<NN/4, 256, 0, stream>>>(xvf, c1w, c1b, c2w, c2b, (float*)d_out);

  hipError_t e = hipGetLastError();
  if (e != hipSuccess){
    sentinel_kernel<<<1, 32, 0, stream>>>((float*)d_out, 10000.f + (float)e);
  }
  (void)in_sizes; (void)n_in; (void)out_size;
}

// Round 19
// 787.084 us; speedup vs baseline: 1.0274x; 1.0063x over previous
//
#include <hip/hip_runtime.h>

#define NN 20000
#define NE 160000
#define HD 128
#define SA 136   // LDS A-tile row stride (bf16 elems); 272B rows, 16B-aligned

typedef __attribute__((ext_vector_type(8))) short  bfrag;   // 8 bf16 = one MFMA A/B frag
typedef __attribute__((ext_vector_type(4))) short  s4v;     // half-frag (8B)
typedef __attribute__((ext_vector_type(4))) float  facc;    // MFMA C/D frag
typedef __attribute__((ext_vector_type(4))) float  f4v;

__device__ __forceinline__ float bf2f(unsigned short u){
  union { unsigned int i; float f; } v; v.i = ((unsigned int)u) << 16; return v.f;
}
__device__ __forceinline__ unsigned short f2bf(float f){
  union { float f; unsigned int i; } v; v.f = f;
  unsigned int r = v.i + 0x7fffu + ((v.i >> 16) & 1u);
  return (unsigned short)(r >> 16);
}

__global__ void sentinel_kernel(float* out, float code){
  if (threadIdx.x < 32) out[threadIdx.x] = code;
}

// A (LDS, [64][SA] bf16) @ B (global, fragment-packed 128x128 bf16) += acc[8]
// packed[((kt*8+nt)*64+lane)*8+j] = W[kt*32+(lane>>4)*8+j][nt*16+(lane&15)]
__device__ __forceinline__ void gemm_tile(const short* Ab,
                                          const unsigned short* pk,
                                          int m0, int lane, facc acc[8]){
  const int q = lane >> 4, c = lane & 15;
  #pragma unroll
  for (int kt = 0; kt < 4; ++kt){
    bfrag a = *(const bfrag*)(Ab + (m0 + c) * SA + kt * 32 + q * 8);
    const bfrag* bp = (const bfrag*)pk + kt * 512 + lane;
    #pragma unroll
    for (int nt = 0; nt < 8; ++nt){
      acc[nt] = __builtin_amdgcn_mfma_f32_16x16x32_bf16(a, bp[nt * 64], acc[nt], 0, 0, 0);
    }
  }
}

// nt-split half-tile: wave computes rows m0..m0+15 x cols [ntb*16, ntb*16+64).
// Per-acc accumulation order (kt outer, nt inner) identical to gemm_tile -> bitwise same.
__device__ __forceinline__ void gemm_tile_h(const short* Ab,
                                            const unsigned short* pk,
                                            int m0, int ntb, int lane, facc acc[4]){
  const int q = lane >> 4, c = lane & 15;
  #pragma unroll
  for (int kt = 0; kt < 4; ++kt){
    bfrag a = *(const bfrag*)(Ab + (m0 + c) * SA + kt * 32 + q * 8);
    const bfrag* bp = (const bfrag*)pk + kt * 512 + ntb * 64 + lane;
    #pragma unroll
    for (int nt = 0; nt < 4; ++nt){
      acc[nt] = __builtin_amdgcn_mfma_f32_16x16x32_bf16(a, bp[nt * 64], acc[nt], 0, 0, 0);
    }
  }
}

// 2-row-set variant: wave computes rows m0..m0+31 x cols [ntb*16, ntb*16+64).
// Each B fragment loaded ONCE feeds 2 MFMAs (row sets m0, m0+16) -> B L2-traffic halved.
// Per-acc order: acc0/acc1 each get one MFMA per kt in kt order -> bitwise identical
// to gemm_tile_h(m0) / gemm_tile_h(m0+16).
__device__ __forceinline__ void gemm_tile_h2(const short* Ab,
                                             const unsigned short* pk,
                                             int m0, int ntb, int lane,
                                             facc acc0[4], facc acc1[4]){
  const int q = lane >> 4, c = lane & 15;
  #pragma unroll
  for (int kt = 0; kt < 4; ++kt){
    bfrag a0 = *(const bfrag*)(Ab + (m0 +      c) * SA + kt * 32 + q * 8);
    bfrag a1 = *(const bfrag*)(Ab + (m0 + 16 + c) * SA + kt * 32 + q * 8);
    const bfrag* bp = (const bfrag*)pk + kt * 512 + ntb * 64 + lane;
    #pragma unroll
    for (int nt = 0; nt < 4; ++nt){
      bfrag b = bp[nt * 64];
      acc0[nt] = __builtin_amdgcn_mfma_f32_16x16x32_bf16(a0, b, acc0[nt], 0, 0, 0);
      acc1[nt] = __builtin_amdgcn_mfma_f32_16x16x32_bf16(a1, b, acc1[nt], 0, 0, 0);
    }
  }
}

// -------- pack 30 fp32 128x128 matrices -> hi/lo bf16 fragment planes (60 planes) --------
__global__ __launch_bounds__(256) void pack_all(
    const float* Wn2, const float* We2,
    const float* lEW1, const float* lEW2,
    const float* lVW1, const float* lVW2,
    unsigned short* packed)
{
  int job = blockIdx.x * 256 + threadIdx.x;   // 30 mats * 4096 (2 planes * 2048)
  int mat = job >> 12, r12 = job & 4095;
  int plane = r12 >> 11, r = r12 & 2047;
  int kt = r >> 9, nt = (r >> 6) & 7, lane = r & 63;
  const float* src;
  if (mat == 0) src = Wn2;
  else if (mat == 1) src = We2;
  else {
    int m2 = mat - 2, l = m2 / 7, t = m2 % 7;
    switch (t){
      case 0: src = lEW1 + ((size_t)l*512 +   0)*HD; break;   // P weights
      case 1: src = lEW1 + ((size_t)l*512 + 128)*HD; break;   // Q weights
      case 2: src = lEW1 + ((size_t)l*512 + 256)*HD; break;   // xe weights
      case 3: src = lEW2 + (size_t)l*HD*HD;          break;
      case 4: src = lVW1 + ((size_t)l*384 +   0)*HD; break;   // x_v weights
      case 5: src = lVW1 + ((size_t)l*384 + 128)*HD; break;   // aggr weights
      default: src = lVW2 + (size_t)l*HD*HD;         break;
    }
  }
  int krow = kt*32 + (lane>>4)*8, col = nt*16 + (lane&15);
  unsigned short v[8];
  #pragma unroll
  for (int j = 0; j < 8; ++j){
    float w = src[(size_t)(krow + j)*HD + col];
    unsigned short h = f2bf(w);
    v[j] = plane ? f2bf(w - bf2f(h)) : h;
  }
  unsigned short* dst = packed + ((size_t)mat*2 + plane)*16384
                               + ((size_t)(kt*8+nt)*64 + lane)*8;
  #pragma unroll
  for (int j = 0; j < 8; ++j) dst[j] = v[j];
}

// ---------------- init ----------------
__global__ __launch_bounds__(128) void init_small(
    float* g, float* cbe, float* cbv, float* xvs, float* xes,
    const float* Eb1_0, const float* Vb1_0)
{
  int t = threadIdx.x;
  g[t] = 0.f; xvs[t] = 0.f; xes[t] = 0.f;
  cbe[t] = Eb1_0[t]; cbv[t] = Vb1_0[t];
}

// ---------------- preprocessing: counting sort of edges by receiver ----------------
__global__ __launch_bounds__(256) void zero_cnt(int* cnt){
  int i = blockIdx.x * 256 + threadIdx.x;
  if (i < NN) cnt[i] = 0;
}
__global__ __launch_bounds__(256) void hist_kernel(const int* eidx, int* cnt){
  int e = blockIdx.x * 256 + threadIdx.x;
  atomicAdd(&cnt[eidx[NE + e]], 1);
}
// exclusive prefix sum over NN counts -> base[0..NN], plus mutable copy ofs
__global__ __launch_bounds__(1024) void scan_kernel(const int* cnt, int* base, int* ofs){
  __shared__ int wsum[16];
  int t = threadIdx.x, lane = t & 63;
  int vals[20]; int loc = 0;
  if (t < 1000){
    #pragma unroll
    for (int k = 0; k < 20; ++k){ vals[k] = cnt[t*20 + k]; loc += vals[k]; }
  }
  int inc = loc;
  #pragma unroll
  for (int d = 1; d < 64; d <<= 1){ int o = __shfl_up(inc, d); if (lane >= d) inc += o; }
  if (lane == 63) wsum[t >> 6] = inc;
  __syncthreads();
  if (t < 16){
    int v = wsum[t];
    #pragma unroll
    for (int d = 1; d < 16; d <<= 1){ int o = __shfl_up(v, d); if (t >= d) v += o; }
    wsum[t] = v;
  }
  __syncthreads();
  int woff = (t >= 64) ? wsum[(t >> 6) - 1] : 0;
  int run = woff + inc - loc;   // exclusive prefix for this thread's chunk
  if (t < 1000){
    #pragma unroll
    for (int k = 0; k < 20; ++k){ base[t*20 + k] = run; ofs[t*20 + k] = run; run += vals[k]; }
  }
  if (t == 0) base[NN] = NE;
}
__global__ __launch_bounds__(256) void scatter_kernel(const int* eidx, int* ofs,
                                                      int* perm, int* ssid, int* srid){
  int e = blockIdx.x * 256 + threadIdx.x;
  int s = eidx[e], r = eidx[NE + e];
  int pos = atomicAdd(&ofs[r], 1);
  perm[pos] = e; ssid[pos] = s; srid[pos] = r;
}

// ---------------- node encoder v2: 512 threads, 8 waves nt-split, LN half-exchange ------
__global__ __launch_bounds__(512, 4) void enc_node(
    const float* x, const float* W1, const float* b1,
    const unsigned short* pkW2, const float* b2,
    const float* gl, const float* bl, float* xvf, int nrows)
{
  __shared__ float inb[64*12];
  __shared__ __align__(16) short Hh[64*SA];
  __shared__ __align__(16) short Hl[64*SA];
  __shared__ float lnS[128], lnSS[128];        // [row*2 + half]
  int tid = threadIdx.x, r0 = blockIdx.x * 64;
  for (int j = tid; j < 64*12; j += 512){
    int rr = j / 12, k = j % 12, rg = r0 + rr;
    inb[j] = (rg < nrows) ? x[(size_t)rg*12 + k] : 0.f;
  }
  __syncthreads();
  {
    int cc = tid & 127;
    float w1c[12];
    #pragma unroll
    for (int k = 0; k < 12; ++k) w1c[k] = W1[k*HD + cc];
    float bb = b1[cc];
    for (int it = 0; it < 16; ++it){
      int rr = it*4 + (tid >> 7);
      float a = bb;
      #pragma unroll
      for (int k = 0; k < 12; ++k) a += inb[rr*12 + k] * w1c[k];
      float h = fmaxf(a, 0.f);
      unsigned short hh = f2bf(h);
      Hh[rr*SA + cc] = (short)hh;
      Hl[rr*SA + cc] = (short)f2bf(h - bf2f(hh));
    }
  }
  __syncthreads();
  int lane = tid & 63, wq = tid >> 6, q = lane >> 4, c = lane & 15;
  int m0 = (wq & 3) * 16, ntb = (wq >> 2) * 4, half = wq >> 2;
  facc a2[4];
  #pragma unroll
  for (int nt = 0; nt < 4; ++nt) a2[nt] = (facc){0.f,0.f,0.f,0.f};
  gemm_tile_h(Hh, pkW2,         m0, ntb, lane, a2);
  gemm_tile_h(Hl, pkW2,         m0, ntb, lane, a2);
  gemm_tile_h(Hh, pkW2 + 16384, m0, ntb, lane, a2);
  float vals[4][4], myS[4], mySS[4];
  #pragma unroll
  for (int i = 0; i < 4; ++i){
    int rl = m0 + q*4 + i;
    float s = 0.f, ss = 0.f;
    #pragma unroll
    for (int nt = 0; nt < 4; ++nt){
      float v = a2[nt][i] + b2[(ntb + nt)*16 + c];
      vals[i][nt] = v; s += v; ss += v*v;
    }
    s += __shfl_xor(s,1); ss += __shfl_xor(ss,1);
    s += __shfl_xor(s,2); ss += __shfl_xor(ss,2);
    s += __shfl_xor(s,4); ss += __shfl_xor(ss,4);
    s += __shfl_xor(s,8); ss += __shfl_xor(ss,8);
    myS[i] = s; mySS[i] = ss;
    if (c == 0){ lnS[rl*2 + half] = s; lnSS[rl*2 + half] = ss; }
  }
  __syncthreads();
  #pragma unroll
  for (int i = 0; i < 4; ++i){
    int rl = m0 + q*4 + i, rg = r0 + rl;
    float sT  = myS[i]  + lnS[rl*2 + (half^1)];
    float ssT = mySS[i] + lnSS[rl*2 + (half^1)];
    float mean = sT * 0.0078125f;
    float var  = ssT * 0.0078125f - mean*mean;
    float rs   = rsqrtf(var + 1e-5f);
    if (rg < nrows){
      #pragma unroll
      for (int nt = 0; nt < 4; ++nt){
        int col = (ntb + nt)*16 + c;
        xvf[(size_t)rg*HD + col] = (vals[i][nt]-mean)*rs*gl[col] + bl[col];
      }
    }
  }
}

// ---------------- edge encoder v2: 512 threads, 8 waves nt-split, LN half-exchange ------
// writes xeb in RECEIVER-SORTED order (row j = edge perm[j])
__global__ __launch_bounds__(512, 4) void enc_edge(
    const float* ea, const int* perm, const float* W1, const float* b1,
    const unsigned short* pkW2, const float* b2,
    const float* gl, const float* bl, unsigned short* xeb)
{
  __shared__ float inb[64*4];
  __shared__ __align__(16) short Hh[64*SA];
  __shared__ __align__(16) short Hl[64*SA];
  __shared__ float lnS[128], lnSS[128];        // [row*2 + half]
  int tid = threadIdx.x, r0 = blockIdx.x * 64;
  if (tid < 256){
    int rr = tid >> 2, k = tid & 3;
    int pe = perm[r0 + rr];
    inb[tid] = ea[(size_t)pe*4 + k];
  }
  __syncthreads();
  {
    int cc = tid & 127;
    float w0 = W1[0*HD+cc], w1 = W1[1*HD+cc], w2 = W1[2*HD+cc], w3 = W1[3*HD+cc];
    float bb = b1[cc];
    for (int it = 0; it < 16; ++it){
      int rr = it*4 + (tid >> 7);
      float a = bb + inb[rr*4+0]*w0 + inb[rr*4+1]*w1 + inb[rr*4+2]*w2 + inb[rr*4+3]*w3;
      float h = fmaxf(a, 0.f);
      unsigned short hh = f2bf(h);
      Hh[rr*SA + cc] = (short)hh;
      Hl[rr*SA + cc] = (short)f2bf(h - bf2f(hh));
    }
  }
  __syncthreads();
  int lane = tid & 63, wq = tid >> 6, q = lane >> 4, c = lane & 15;
  int m0 = (wq & 3) * 16, ntb = (wq >> 2) * 4, half = wq >> 2;
  facc a2[4];
  #pragma unroll
  for (int nt = 0; nt < 4; ++nt) a2[nt] = (facc){0.f,0.f,0.f,0.f};
  gemm_tile_h(Hh, pkW2,         m0, ntb, lane, a2);
  gemm_tile_h(Hl, pkW2,         m0, ntb, lane, a2);
  gemm_tile_h(Hh, pkW2 + 16384, m0, ntb, lane, a2);
  float vals[4][4], myS[4], mySS[4];
  #pragma unroll
  for (int i = 0; i < 4; ++i){
    int rl = m0 + q*4 + i;
    float s = 0.f, ss = 0.f;
    #pragma unroll
    for (int nt = 0; nt < 4; ++nt){
      float v = a2[nt][i] + b2[(ntb + nt)*16 + c];
      vals[i][nt] = v; s += v; ss += v*v;
    }
    s += __shfl_xor(s,1); ss += __shfl_xor(ss,1);
    s += __shfl_xor(s,2); ss += __shfl_xor(ss,2);
    s += __shfl_xor(s,4); ss += __shfl_xor(ss,4);
    s += __shfl_xor(s,8); ss += __shfl_xor(ss,8);
    myS[i] = s; mySS[i] = ss;
    if (c == 0){ lnS[rl*2 + half] = s; lnSS[rl*2 + half] = ss; }
  }
  __syncthreads();
  #pragma unroll
  for (int i = 0; i < 4; ++i){
    int rl = m0 + q*4 + i, rg = r0 + rl;
    float sT  = myS[i]  + lnS[rl*2 + (half^1)];
    float ssT = mySS[i] + lnSS[rl*2 + (half^1)];
    float mean = sT * 0.0078125f;
    float var  = ssT * 0.0078125f - mean*mean;
    float rs   = rsqrtf(var + 1e-5f);
    #pragma unroll
    for (int nt = 0; nt < 4; ++nt){
      int col = (ntb + nt)*16 + c;
      xeb[(size_t)rg*HD + col] = f2bf((vals[i][nt]-mean)*rs*gl[col] + bl[col]);
    }
  }
}

// ---- P,Q = x_v @ EW1[0:128], @ EW1[128:256] — 8 waves, nt-split halves (layer 0 only) ----
__global__ __launch_bounds__(512, 4) void pq_kernel(
    const float* xvf, const unsigned short* pkA, const unsigned short* pkB,
    unsigned short* P, unsigned short* Q, int nrows)
{
  __shared__ __align__(16) short Ah[64*SA];
  __shared__ __align__(16) short Al[64*SA];
  int tid = threadIdx.x, r0 = blockIdx.x * 64;
  for (int j = tid; j < 1024; j += 512){
    int rr = j >> 4, ch = j & 15, rg = r0 + rr;
    float v[8];
    if (rg < nrows){
      f4v a = *(const f4v*)(xvf + (size_t)rg*HD + ch*8);
      f4v b = *(const f4v*)(xvf + (size_t)rg*HD + ch*8 + 4);
      v[0]=a[0];v[1]=a[1];v[2]=a[2];v[3]=a[3];v[4]=b[0];v[5]=b[1];v[6]=b[2];v[7]=b[3];
    } else {
      #pragma unroll
      for (int k = 0; k < 8; ++k) v[k] = 0.f;
    }
    short* dh = Ah + rr*SA + ch*8;
    short* dl = Al + rr*SA + ch*8;
    #pragma unroll
    for (int k = 0; k < 8; ++k){
      unsigned short h = f2bf(v[k]);
      dh[k] = (short)h; dl[k] = (short)f2bf(v[k] - bf2f(h));
    }
  }
  __syncthreads();
  int lane = tid & 63, wq = tid >> 6, q = lane >> 4, c = lane & 15;
  int m0 = (wq & 3) * 16, ntb = (wq >> 2) * 4;
  facc ap[4], aq[4];
  #pragma unroll
  for (int nt = 0; nt < 4; ++nt){ ap[nt] = (facc){0.f,0.f,0.f,0.f}; aq[nt] = (facc){0.f,0.f,0.f,0.f}; }
  gemm_tile_h(Ah, pkA,         m0, ntb, lane, ap);
  gemm_tile_h(Al, pkA,         m0, ntb, lane, ap);
  gemm_tile_h(Ah, pkA + 16384, m0, ntb, lane, ap);
  gemm_tile_h(Ah, pkB,         m0, ntb, lane, aq);
  gemm_tile_h(Al, pkB,         m0, ntb, lane, aq);
  gemm_tile_h(Ah, pkB + 16384, m0, ntb, lane, aq);
  #pragma unroll
  for (int i = 0; i < 4; ++i){
    int rl = m0 + q*4 + i, rg = r0 + rl;
    if (rg < nrows){
      s4v pv, qv;
      #pragma unroll
      for (int nt = 0; nt < 4; ++nt){
        pv[nt] = (short)f2bf(ap[nt][i]);
        qv[nt] = (short)f2bf(aq[nt][i]);
      }
      *(s4v*)(P + (size_t)rg*HD + c*8 + ntb) = pv;   // [row][c][nt] fragment layout
      *(s4v*)(Q + (size_t)rg*HD + c*8 + ntb) = qv;
    }
  }
}

// ---------------- edge update v9: 64 edges/block, 4 waves of 32 rows x 64 cols ------------
// ---------------- (gemm_tile_h2: each B frag feeds 2 MFMAs -> B L2-traffic halved) --------
__global__ __launch_bounds__(256, 3) void edge_kernel(
    unsigned short* xeb, const int* ssid, const int* srid,
    const unsigned short* P, const unsigned short* Q, const float* cbe,
    const unsigned short* pkW1c, const unsigned short* pkW2,
    const float* Eb2, const float* Eg, const float* Ebt)
{
  __shared__ __align__(16) short Ab[64*SA];    // becomes Hh after gemm1
  __shared__ __align__(16) short Hl[64*SA];
  __shared__ float lnS[128], lnSS[128];        // [row*2 + half]
  int tid = threadIdx.x, e0 = blockIdx.x * 64;
  int lane = tid & 63, wq = tid >> 6, q = lane >> 4, c = lane & 15;
  int m0 = (wq & 1) * 32, ntb = (wq >> 1) * 4, half = wq >> 1;

  // early: sender/receiver ids (L1-broadcast) + P/Q gathers for this thread's 8 rows,
  // issued BEFORE the staging barrier so latency hides under Ab staging.
  float pg[2][4][4];
  {
    float cb[4];
    #pragma unroll
    for (int nt = 0; nt < 4; ++nt) cb[nt] = cbe[(ntb + nt)*16 + c];
    #pragma unroll
    for (int rs = 0; rs < 2; ++rs){
      #pragma unroll
      for (int i = 0; i < 4; ++i){
        int rl = m0 + rs*16 + q*4 + i;
        int sid = ssid[e0 + rl], rid = srid[e0 + rl];
        s4v ps = *(const s4v*)(P + (size_t)sid*HD + c*8 + ntb);
        s4v qr = *(const s4v*)(Q + (size_t)rid*HD + c*8 + ntb);
        #pragma unroll
        for (int nt = 0; nt < 4; ++nt)
          pg[rs][i][nt] = bf2f((unsigned short)ps[nt]) + bf2f((unsigned short)qr[nt]) + cb[nt];
      }
    }
  }

  for (int j = tid; j < 1024; j += 256){
    int rr = j >> 4, ch = j & 15;
    *(bfrag*)(Ab + rr*SA + ch*8) = *(const bfrag*)(xeb + (size_t)(e0+rr)*HD + ch*8);
  }
  __syncthreads();

  // residual (bf16) for this thread's 8 rows x 4-col quadrant, packed 2 per u32 (16 VGPRs)
  unsigned int rres[2][4][2];
  #pragma unroll
  for (int rs = 0; rs < 2; ++rs){
    #pragma unroll
    for (int i = 0; i < 4; ++i){
      int rl = m0 + rs*16 + q*4 + i;
      #pragma unroll
      for (int p2 = 0; p2 < 2; ++p2){
        unsigned short a0 = (unsigned short)Ab[rl*SA + (ntb + 2*p2    )*16 + c];
        unsigned short a1 = (unsigned short)Ab[rl*SA + (ntb + 2*p2 + 1)*16 + c];
        rres[rs][i][p2] = ((unsigned int)a1 << 16) | a0;
      }
    }
  }
  facc acc0[4], acc1[4];
  #pragma unroll
  for (int nt = 0; nt < 4; ++nt){ acc0[nt] = (facc){0.f,0.f,0.f,0.f}; acc1[nt] = (facc){0.f,0.f,0.f,0.f}; }
  gemm_tile_h2(Ab, pkW1c,         m0, ntb, lane, acc0, acc1);   // xe exact bf16 -> 2 products
  gemm_tile_h2(Ab, pkW1c + 16384, m0, ntb, lane, acc0, acc1);
  __syncthreads();   // all Ab reads (gemm1 A-frags + rres) complete before overwrite
  #pragma unroll
  for (int rs = 0; rs < 2; ++rs){
    #pragma unroll
    for (int i = 0; i < 4; ++i){
      int rl = m0 + rs*16 + q*4 + i;
      #pragma unroll
      for (int nt = 0; nt < 4; ++nt){
        int col = (ntb + nt)*16 + c;
        float av = rs ? acc1[nt][i] : acc0[nt][i];
        float h = fmaxf(av + pg[rs][i][nt], 0.f);
        unsigned short hh = f2bf(h);
        Ab[rl*SA + col] = (short)hh;           // Hh in-place
        Hl[rl*SA + col] = (short)f2bf(h - bf2f(hh));
      }
    }
  }
  __syncthreads();
  facc a20[4], a21[4];
  #pragma unroll
  for (int nt = 0; nt < 4; ++nt){ a20[nt] = (facc){0.f,0.f,0.f,0.f}; a21[nt] = (facc){0.f,0.f,0.f,0.f}; }
  gemm_tile_h2(Ab, pkW2,         m0, ntb, lane, a20, a21);
  gemm_tile_h2(Hl, pkW2,         m0, ntb, lane, a20, a21);
  gemm_tile_h2(Ab, pkW2 + 16384, m0, ntb, lane, a20, a21);
  // ---- LN: 64-col partials per row, exchanged across the col-half wave pair via LDS ----
  float vals[2][4][4], myS[2][4], mySS[2][4];
  #pragma unroll
  for (int rs = 0; rs < 2; ++rs){
    #pragma unroll
    for (int i = 0; i < 4; ++i){
      int rl = m0 + rs*16 + q*4 + i;
      float s = 0.f, ss = 0.f;
      #pragma unroll
      for (int nt = 0; nt < 4; ++nt){
        float v = (rs ? a21[nt][i] : a20[nt][i]) + Eb2[(ntb + nt)*16 + c];
        vals[rs][i][nt] = v; s += v; ss += v*v;
      }
      s += __shfl_xor(s,1); ss += __shfl_xor(ss,1);
      s += __shfl_xor(s,2); ss += __shfl_xor(ss,2);
      s += __shfl_xor(s,4); ss += __shfl_xor(ss,4);
      s += __shfl_xor(s,8); ss += __shfl_xor(ss,8);
      myS[rs][i] = s; mySS[rs][i] = ss;
      if (c == 0){ lnS[rl*2 + half] = s; lnSS[rl*2 + half] = ss; }
    }
  }
  __syncthreads();
  #pragma unroll
  for (int rs = 0; rs < 2; ++rs){
    #pragma unroll
    for (int i = 0; i < 4; ++i){
      int rl = m0 + rs*16 + q*4 + i, eg = e0 + rl;
      float sT  = myS[rs][i]  + lnS[rl*2 + (half^1)];
      float ssT = mySS[rs][i] + lnSS[rl*2 + (half^1)];
      float mean = sT * 0.0078125f;
      float var  = ssT * 0.0078125f - mean*mean;
      float rs2  = rsqrtf(var + 1e-5f);
      #pragma unroll
      for (int nt = 0; nt < 4; ++nt){
        int col = (ntb + nt)*16 + c;
        float o = (vals[rs][i][nt]-mean)*rs2*Eg[col] + Ebt[col];
        float rv = bf2f((unsigned short)(rres[rs][i][nt >> 1] >> ((nt & 1)*16)));
        xeb[(size_t)eg*HD + col] = f2bf(rv + o);
      }
    }
  }
}

// ---------------- node update v8: 32 nodes/block, 4 waves; launch_bounds(256,2) ---------
// ---------------- (VGPR cap 64 -> 128: deeper B-load pipelining) + PQ tail --------------
__global__ __launch_bounds__(256, 2) void node_kernel(
    float* xvf, const unsigned short* xeb, const int* base, const float* cbv,
    const unsigned short* pkW1a, const unsigned short* pkW1b, const unsigned short* pkW2,
    const float* Vb2, const float* Vg, const float* Vbt,
    float* xv_sum, float* xes, int do_xes,
    const unsigned short* pkAn, const unsigned short* pkBn,
    unsigned short* P, unsigned short* Q, int do_pq, int nrows)
{
  __shared__ __align__(16) short Avh[32*SA];   // reused as Hh after MLP1
  __shared__ __align__(16) short Avl[32*SA];   // reused as Hl
  __shared__ __align__(16) short Agh[32*SA];   // aggr; reused as xv_new-hi for PQ tail
  __shared__ __align__(16) short Agl[32*SA];   // aggr-lo; reused as xv_new-lo
  __shared__ float red[128];
  __shared__ float lnS[64], lnSS[64];          // [row*2 + half]
  int tid = threadIdx.x, r0 = blockIdx.x * 32;
  int lane = tid & 63, wq = tid >> 6;          // 4 waves
  if (tid < 128) red[tid] = 0.f;
  __syncthreads();   // red init visible before aggregation atomics
  // ---- stage x_v (hi/lo split): 32 rows x 16 chunks = 512 jobs ----
  for (int j = tid; j < 512; j += 256){
    int rr = j >> 4, ch = j & 15, rg = r0 + rr;
    float v[8];
    if (rg < nrows){
      f4v a = *(const f4v*)(xvf + (size_t)rg*HD + ch*8);
      f4v b = *(const f4v*)(xvf + (size_t)rg*HD + ch*8 + 4);
      v[0]=a[0];v[1]=a[1];v[2]=a[2];v[3]=a[3];v[4]=b[0];v[5]=b[1];v[6]=b[2];v[7]=b[3];
    } else {
      #pragma unroll
      for (int k = 0; k < 8; ++k) v[k] = 0.f;
    }
    short *dvh = Avh + rr*SA + ch*8, *dvl = Avl + rr*SA + ch*8;
    #pragma unroll
    for (int k = 0; k < 8; ++k){
      unsigned short h1 = f2bf(v[k]);
      dvh[k] = (short)h1; dvl[k] = (short)f2bf(v[k] - bf2f(h1));
    }
  }
  // ---- fused aggregation: wave wq sums nodes r0+wq*8 .. +7; lane covers cols 2l,2l+1 ----
  // 8-wide load batching: 8 independent loads in flight; accumulation stays in the
  // exact pairwise order of the 2-wide loop -> bitwise identical sums.
  float xp0 = 0.f, xp1 = 0.f;
  for (int j = 0; j < 8; ++j){
    int rl = wq*8 + j, rg = r0 + rl;
    float s0 = 0.f, s1 = 0.f;
    if (rg < nrows){
      int b0 = base[rg], b1 = base[rg + 1];
      int e = b0;
      for (; e + 7 < b1; e += 8){
        unsigned int u[8];
        #pragma unroll
        for (int k = 0; k < 8; ++k)
          u[k] = *(const unsigned int*)(xeb + (size_t)(e+k)*HD + lane*2);
        #pragma unroll
        for (int k = 0; k < 8; k += 2){
          s0 += bf2f((unsigned short)(u[k] & 0xffffu)) + bf2f((unsigned short)(u[k+1] & 0xffffu));
          s1 += bf2f((unsigned short)(u[k] >> 16))     + bf2f((unsigned short)(u[k+1] >> 16));
        }
      }
      for (; e + 1 < b1; e += 2){
        unsigned int u0 = *(const unsigned int*)(xeb + (size_t)e*HD + lane*2);
        unsigned int u1 = *(const unsigned int*)(xeb + (size_t)(e+1)*HD + lane*2);
        s0 += bf2f((unsigned short)(u0 & 0xffffu)) + bf2f((unsigned short)(u1 & 0xffffu));
        s1 += bf2f((unsigned short)(u0 >> 16))     + bf2f((unsigned short)(u1 >> 16));
      }
      if (e < b1){
        unsigned int u0 = *(const unsigned int*)(xeb + (size_t)e*HD + lane*2);
        s0 += bf2f((unsigned short)(u0 & 0xffffu));
        s1 += bf2f((unsigned short)(u0 >> 16));
      }
    }
    unsigned short h0 = f2bf(s0), h1 = f2bf(s1);
    unsigned short l0 = f2bf(s0 - bf2f(h0)), l1 = f2bf(s1 - bf2f(h1));
    *(unsigned int*)(Agh + rl*SA + 2*lane) = ((unsigned int)h1 << 16) | h0;
    *(unsigned int*)(Agl + rl*SA + 2*lane) = ((unsigned int)l1 << 16) | l0;
    xp0 += s0; xp1 += s1;
  }
  if (do_xes){
    atomicAdd(&red[lane*2],     xp0);
    atomicAdd(&red[lane*2 + 1], xp1);
  }
  __syncthreads();
  if (do_xes && tid < 128) atomicAdd(&xes[tid], red[tid]);
  int q = lane >> 4, c = lane & 15;
  int m0 = (wq & 1) * 16, ntb = (wq >> 1) * 4, half = wq >> 1;
  facc acc[4];
  #pragma unroll
  for (int nt = 0; nt < 4; ++nt) acc[nt] = (facc){0.f,0.f,0.f,0.f};
  gemm_tile_h(Avh, pkW1a,         m0, ntb, lane, acc);
  gemm_tile_h(Avl, pkW1a,         m0, ntb, lane, acc);
  gemm_tile_h(Avh, pkW1a + 16384, m0, ntb, lane, acc);
  gemm_tile_h(Agh, pkW1b,         m0, ntb, lane, acc);
  gemm_tile_h(Agl, pkW1b,         m0, ntb, lane, acc);
  gemm_tile_h(Agh, pkW1b + 16384, m0, ntb, lane, acc);
  __syncthreads();   // everyone done reading Av/Ag planes before overwrite
  #pragma unroll
  for (int i = 0; i < 4; ++i){
    int rl = m0 + q*4 + i;
    #pragma unroll
    for (int nt = 0; nt < 4; ++nt){
      int col = (ntb + nt)*16 + c;
      float h = fmaxf(acc[nt][i] + cbv[col], 0.f);
      unsigned short hh = f2bf(h);
      Avh[rl*SA + col] = (short)hh;          // Hh
      Avl[rl*SA + col] = (short)f2bf(h - bf2f(hh)); // Hl
    }
  }
  __syncthreads();
  facc a2[4];
  #pragma unroll
  for (int nt = 0; nt < 4; ++nt) a2[nt] = (facc){0.f,0.f,0.f,0.f};
  gemm_tile_h(Avh, pkW2,         m0, ntb, lane, a2);
  gemm_tile_h(Avl, pkW2,         m0, ntb, lane, a2);
  gemm_tile_h(Avh, pkW2 + 16384, m0, ntb, lane, a2);
  // ---- LN: 64-col partials per wave, exchanged across the wave pair via LDS ----
  float vals[4][4], myS[4], mySS[4];
  #pragma unroll
  for (int i = 0; i < 4; ++i){
    int rl = m0 + q*4 + i;
    float s = 0.f, ss = 0.f;
    #pragma unroll
    for (int nt = 0; nt < 4; ++nt){
      float v = a2[nt][i] + Vb2[(ntb + nt)*16 + c];
      vals[i][nt] = v; s += v; ss += v*v;
    }
    s += __shfl_xor(s,1); ss += __shfl_xor(ss,1);
    s += __shfl_xor(s,2); ss += __shfl_xor(ss,2);
    s += __shfl_xor(s,4); ss += __shfl_xor(ss,4);
    s += __shfl_xor(s,8); ss += __shfl_xor(ss,8);
    myS[i] = s; mySS[i] = ss;
    if (c == 0){ lnS[rl*2 + half] = s; lnSS[rl*2 + half] = ss; }
  }
  __syncthreads();
  float csum[4] = {0.f,0.f,0.f,0.f};
  #pragma unroll
  for (int i = 0; i < 4; ++i){
    int rl = m0 + q*4 + i, rg = r0 + rl;
    float sT  = myS[i]  + lnS[rl*2 + (half^1)];
    float ssT = mySS[i] + lnSS[rl*2 + (half^1)];
    float mean = sT * 0.0078125f;
    float var  = ssT * 0.0078125f - mean*mean;
    float rs   = rsqrtf(var + 1e-5f);
    if (rg < nrows){
      #pragma unroll
      for (int nt = 0; nt < 4; ++nt){
        int col = (ntb + nt)*16 + c;
        float o = (vals[i][nt]-mean)*rs*Vg[col] + Vbt[col];
        size_t gi = (size_t)rg*HD + col;
        float nv = xvf[gi] + o;
        xvf[gi] = nv;
        csum[nt] += nv;
        if (do_pq){   // stage xv_new hi/lo into dead Ag tiles for the PQ tail
          unsigned short hh = f2bf(nv);
          Agh[rl*SA + col] = (short)hh;
          Agl[rl*SA + col] = (short)f2bf(nv - bf2f(hh));
        }
      }
    }
  }
  #pragma unroll
  for (int nt = 0; nt < 4; ++nt){
    float v = csum[nt]; v += __shfl_xor(v,16); v += __shfl_xor(v,32);
    if (q == 0) atomicAdd(&xv_sum[(ntb + nt)*16 + c], v);
  }
  // ---- PQ tail: P,Q for the NEXT layer from xv_new (tail rows stay zero from aggregation) ----
  if (do_pq){
    __syncthreads();   // all xv_new hi/lo writes visible
    facc ap[4], aq[4];
    #pragma unroll
    for (int nt = 0; nt < 4; ++nt){ ap[nt] = (facc){0.f,0.f,0.f,0.f}; aq[nt] = (facc){0.f,0.f,0.f,0.f}; }
    gemm_tile_h(Agh, pkAn,         m0, ntb, lane, ap);
    gemm_tile_h(Agl, pkAn,         m0, ntb, lane, ap);
    gemm_tile_h(Agh, pkAn + 16384, m0, ntb, lane, ap);
    gemm_tile_h(Agh, pkBn,         m0, ntb, lane, aq);
    gemm_tile_h(Agl, pkBn,         m0, ntb, lane, aq);
    gemm_tile_h(Agh, pkBn + 16384, m0, ntb, lane, aq);
    #pragma unroll
    for (int i = 0; i < 4; ++i){
      int rl = m0 + q*4 + i, rg = r0 + rl;
      if (rg < nrows){
        s4v pv, qv;
        #pragma unroll
        for (int nt = 0; nt < 4; ++nt){
          pv[nt] = (short)f2bf(ap[nt][i]);
          qv[nt] = (short)f2bf(aq[nt][i]);
        }
        *(s4v*)(P + (size_t)rg*HD + c*8 + ntb) = pv;
        *(s4v*)(Q + (size_t)rg*HD + c*8 + ntb) = qv;
      }
    }
  }
}

// ---------------- global-state update + next-layer bias fold (1024 threads, 8-way k-split) ----
__global__ __launch_bounds__(1024) void g_kernel(
    float* xvs, float* xes, float* g,
    const float* GW1, const float* Gb1, const float* GW2, const float* Gb2,
    const float* Gg, const float* Gbt,
    float* cbe, float* cbv,
    const float* EW1n, const float* Eb1n, const float* VW1n, const float* Vb1n)
{
  __shared__ float gin[384], h1[128], gn[128], red[4];
  __shared__ float partA[8][128], partB[8][128];
  int tid = threadIdx.x, t = tid & 127, kk = tid >> 7;   // kk in 0..7
  if (tid < 384) gin[tid] = (tid < 128) ? xvs[tid] : (tid < 256) ? xes[tid-128] : g[tid-256];
  __syncthreads();
  // MLP1: 384 = 8 x 48
  {
    float a = 0.f;
    for (int k = kk*48; k < kk*48 + 48; ++k) a += gin[k] * GW1[(size_t)k*HD + t];
    partA[kk][t] = a;
  }
  __syncthreads();
  if (kk == 0){
    float a = Gb1[t];
    #pragma unroll
    for (int i = 0; i < 8; ++i) a += partA[i][t];
    h1[t] = fmaxf(a, 0.f);
  }
  __syncthreads();
  // MLP2: 128 = 8 x 16
  {
    float o = 0.f;
    for (int k = kk*16; k < kk*16 + 16; ++k) o += h1[k] * GW2[(size_t)k*HD + t];
    partA[kk][t] = o;
  }
  __syncthreads();
  float oo = 0.f;
  if (kk == 0){
    oo = Gb2[t];
    #pragma unroll
    for (int i = 0; i < 8; ++i) oo += partA[i][t];
  }
  __syncthreads();
  if (tid < 128){
    float s = oo;
    #pragma unroll
    for (int d = 1; d < 64; d <<= 1) s += __shfl_xor(s, d);
    if ((tid & 63) == 0) red[tid >> 6] = s;
  }
  __syncthreads();
  float mean = (red[0] + red[1]) * 0.0078125f;
  if (tid < 128){
    float dd = oo - mean;
    float v = dd * dd;
    #pragma unroll
    for (int d = 1; d < 64; d <<= 1) v += __shfl_xor(v, d);
    if ((tid & 63) == 0) red[2 + (tid >> 6)] = v;
  }
  __syncthreads();
  if (tid < 128){
    float rs = rsqrtf((red[2] + red[3]) * 0.0078125f + 1e-5f);
    float gnv = g[tid] + (oo - mean)*rs*Gg[tid] + Gbt[tid];
    g[tid] = gnv; gn[tid] = gnv;
    xvs[tid] = 0.f; xes[tid] = 0.f;
  }
  __syncthreads();
  // bias fold for next layer: 128 = 8 x 16 per output
  {
    float ce = 0.f, cv = 0.f;
    for (int k = kk*16; k < kk*16 + 16; ++k){
      ce += gn[k] * EW1n[(size_t)k*HD + t];
      cv += gn[k] * VW1n[(size_t)k*HD + t];
    }
    partA[kk][t] = ce; partB[kk][t] = cv;
  }
  __syncthreads();
  if (kk == 0){
    float ce = Eb1n[t], cv = Vb1n[t];
    #pragma unroll
    for (int i = 0; i < 8; ++i){ ce += partA[i][t]; cv += partB[i][t]; }
    cbe[t] = ce; cbv[t] = cv;
  }
}

// ---------------- decoder: fp32 in, fp32 out ----------------
__global__ __launch_bounds__(256) void decoder_kernel(
    const float* xv, const float* c1w, const float* c1b,
    const float* c2w, const float* c2b, float* out)
{
  __shared__ float xl[4][128];
  __shared__ float hl[4][232];
  __shared__ float w1[120], b1[8], w2[80];
  __shared__ float b2s;
  int tid = threadIdx.x, nl = tid >> 6, t = tid & 63;
  int n = blockIdx.x * 4 + nl;
  if (tid < 120) w1[tid] = c1w[tid];
  else if (tid < 128) b1[tid - 120] = c1b[tid - 120];
  else if (tid < 208) w2[tid - 128] = c2w[tid - 128];
  else if (tid == 208) b2s = c2b[0];
  xl[nl][t]      = xv[(size_t)n*HD + t];
  xl[nl][t + 64] = xv[(size_t)n*HD + 64 + t];
  __syncthreads();
  for (int j = t; j < 232; j += 64){
    int ch = j / 29, pp = j % 29;
    float a = b1[ch];
    #pragma unroll
    for (int u = 0; u < 15; ++u) a += xl[nl][4*pp + u] * w1[ch*15 + u];
    hl[nl][j] = fmaxf(a, 0.f);
  }
  __syncthreads();
  if (t < 20){
    float o = b2s;
    #pragma unroll
    for (int ch = 0; ch < 8; ++ch)
      #pragma unroll
      for (int u = 0; u < 10; ++u)
        o += hl[nl][ch*29 + t + u] * w2[ch*10 + u];
    out[(size_t)n*20 + t] = o;
  }
}

extern "C" void kernel_launch(void* const* d_in, const int* in_sizes, int n_in,
                              void* d_out, int out_size, void* d_ws, size_t ws_size,
                              hipStream_t stream)
{
  const float* x    = (const float*)d_in[0];
  const float* ea   = (const float*)d_in[1];
  const int*   eidx = (const int*)d_in[2];
  const float* Wn1  = (const float*)d_in[3];  const float* bn1  = (const float*)d_in[4];
  const float* Wn2  = (const float*)d_in[5];  const float* bn2  = (const float*)d_in[6];
  const float* gnln = (const float*)d_in[7];  const float* bnln = (const float*)d_in[8];
  const float* We1  = (const float*)d_in[9];  const float* be1  = (const float*)d_in[10];
  const float* We2  = (const float*)d_in[11]; const float* be2  = (const float*)d_in[12];
  const float* geln = (const float*)d_in[13]; const float* beln = (const float*)d_in[14];
  const float* lEW1 = (const float*)d_in[15]; const float* lEb1 = (const float*)d_in[16];
  const float* lEW2 = (const float*)d_in[17]; const float* lEb2 = (const float*)d_in[18];
  const float* lEg  = (const float*)d_in[19]; const float* lEbt = (const float*)d_in[20];
  const float* lVW1 = (const float*)d_in[21]; const float* lVb1 = (const float*)d_in[22];
  const float* lVW2 = (const float*)d_in[23]; const float* lVb2 = (const float*)d_in[24];
  const float* lVg  = (const float*)d_in[25]; const float* lVbt = (const float*)d_in[26];
  const float* lGW1 = (const float*)d_in[27]; const float* lGb1 = (const float*)d_in[28];
  const float* lGW2 = (const float*)d_in[29]; const float* lGb2 = (const float*)d_in[30];
  const float* lGg  = (const float*)d_in[31]; const float* lGbt = (const float*)d_in[32];
  const float* c1w  = (const float*)d_in[33]; const float* c1b  = (const float*)d_in[34];
  const float* c2w  = (const float*)d_in[35]; const float* c2b  = (const float*)d_in[36];

  char* ws = (char*)d_ws;
  size_t off = 0;
  auto alloc = [&](size_t b){ size_t o = off; off += (b + 255) & ~(size_t)255; return o; };
  unsigned short* pk   = (unsigned short*)(ws + alloc((size_t)30*2*16384*2)); // 1.97 MB hi/lo planes
  float*          g    = (float*)(ws + alloc(512));
  float*          cbe  = (float*)(ws + alloc(512));
  float*          cbv  = (float*)(ws + alloc(512));
  float*          xvs  = (float*)(ws + alloc(512));
  float*          xes  = (float*)(ws + alloc(512));
  float*          xvf  = (float*)(ws + alloc((size_t)NN*HD*4));          // 10.24 MB
  unsigned short* P    = (unsigned short*)(ws + alloc((size_t)NN*HD*2)); //  5.12 MB
  unsigned short* Q    = (unsigned short*)(ws + alloc((size_t)NN*HD*2)); //  5.12 MB
  unsigned short* xeb  = (unsigned short*)(ws + alloc((size_t)NE*HD*2)); // 40.96 MB (sorted order)
  int*            cnt  = (int*)(ws + alloc((size_t)NN*4));
  int*            bse  = (int*)(ws + alloc((size_t)(NN+1)*4));
  int*            ofs  = (int*)(ws + alloc((size_t)NN*4));
  int*            perm = (int*)(ws + alloc((size_t)NE*4));
  int*            ssid = (int*)(ws + alloc((size_t)NE*4));
  int*            srid = (int*)(ws + alloc((size_t)NE*4));

  if (ws_size < off){
    sentinel_kernel<<<1, 32, 0, stream>>>((float*)d_out, 20000.f + (float)(ws_size >> 20));
    return;
  }

  auto slot = [&](int m){ return pk + (size_t)m * 32768; };  // hi at +0, lo at +16384

  pack_all<<<480, 256, 0, stream>>>(Wn2, We2, lEW1, lEW2, lVW1, lVW2, pk);
  init_small<<<1, 128, 0, stream>>>(g, cbe, cbv, xvs, xes, lEb1, lVb1);
  // counting sort of edges by receiver (once per launch)
  zero_cnt<<<(NN + 255)/256, 256, 0, stream>>>(cnt);
  hist_kernel<<<NE/256, 256, 0, stream>>>(eidx, cnt);
  scan_kernel<<<1, 1024, 0, stream>>>(cnt, bse, ofs);
  scatter_kernel<<<NE/256, 256, 0, stream>>>(eidx, ofs, perm, ssid, srid);

  enc_node<<<(NN + 63)/64, 512, 0, stream>>>(x, Wn1, bn1, slot(0), bn2, gnln, bnln, xvf, NN);
  enc_edge<<<NE/64, 512, 0, stream>>>(ea, perm, We1, be1, slot(1), be2, geln, beln, xeb);

  // P/Q for layer 0 (later layers produce P/Q in node_kernel's tail)
  pq_kernel<<<(NN + 63)/64, 512, 0, stream>>>(xvf, slot(2), slot(3), P, Q, NN);

  for (int l = 0; l < 4; ++l){
    int m = 2 + 7*l;
    edge_kernel<<<NE/64, 256, 0, stream>>>(xeb, ssid, srid, P, Q, cbe,
        slot(m+2), slot(m+3),
        lEb2 + (size_t)l*HD, lEg + (size_t)l*HD, lEbt + (size_t)l*HD);
    node_kernel<<<(NN + 31)/32, 256, 0, stream>>>(xvf, xeb, bse, cbv,
        slot(m+4), slot(m+5), slot(m+6),
        lVb2 + (size_t)l*HD, lVg + (size_t)l*HD, lVbt + (size_t)l*HD,
        xvs, xes, (l < 3) ? 1 : 0,
        slot(m+7), slot(m+8), P, Q, (l < 3) ? 1 : 0, NN);
    if (l < 3){
      g_kernel<<<1, 1024, 0, stream>>>(xvs, xes, g,
          lGW1 + (size_t)l*384*HD, lGb1 + (size_t)l*HD,
          lGW2 + (size_t)l*HD*HD, lGb2 + (size_t)l*HD,
          lGg + (size_t)l*HD, lGbt + (size_t)l*HD,
          cbe, cbv,
          lEW1 + ((size_t)(l+1)*512 + 384)*HD, lEb1 + (size_t)(l+1)*HD,
          lVW1 + ((size_t)(l+1)*384 + 256)*HD, lVb1 + (size_t)(l+1)*HD);
    }
  }
  decoder_kernel<<<NN/4, 256, 0, stream>>>(xvf, c1w, c1b, c2w, c2b, (float*)d_out);

  hipError_t e = hipGetLastError();
  if (e != hipSuccess){
    sentinel_kernel<<<1, 32, 0, stream>>>((float*)d_out, 10000.f + (float)e);
  }
  (void)in_sizes; (void)n_in; (void)out_size;
}